// Round 14
// baseline (851.453 us; speedup 1.0000x reference)
//
#include <hip/hip_runtime.h>

// ============ ATTRIBUTION ROUND: k_pack x8, k2 x10, k3 x4 inner reps ============
// Idempotent repeats (same output every rep). Divide profiled dur by the rep
// count for true per-kernel cost. Deliberate dur regression this round.

#define S_TOT 12096
#define REP_PACK 8
#define REP_K2 10
#define REP_K3 4
typedef unsigned short u16;
typedef __attribute__((ext_vector_type(4))) unsigned short u16x4;
typedef __attribute__((ext_vector_type(8))) unsigned short u16x8;
typedef __attribute__((ext_vector_type(8))) short bf16x8;
typedef __attribute__((ext_vector_type(4))) float f32x4;

__device__ __forceinline__ u16 f2bf(float f) {
  union { float f; unsigned u; } v; v.f = f;
  unsigned r = v.u + 0x7FFFu + ((v.u >> 16) & 1u);  // round-nearest-even
  return (u16)(r >> 16);
}

// ---------------------------------------------------------------------------
__global__ __launch_bounds__(256) void k_pack(
    const float* __restrict__ pw, const float* __restrict__ ow,
    const float* __restrict__ f1w, const float* __restrict__ f2w,
    u16* __restrict__ dst) {
  __shared__ float ls[16384];   // 64 KB tile
  const int t = threadIdx.x;
  const int bid = blockIdx.x;   // 0..39
  const float* src; int nc, KC, base8, r0;
  if (bid < 4)       { src = pw;  nc = 256;  KC = 8;  base8 = 0;     r0 = bid * 64; }
  else if (bid < 8)  { src = ow;  nc = 256;  KC = 8;  base8 = 8192;  r0 = (bid - 4) * 64; }
  else if (bid < 24) { src = f2w; nc = 256;  KC = 32; base8 = 49152; r0 = (bid - 8) * 64; }
  else               { src = f1w; nc = 1024; KC = 8;  base8 = 16384; r0 = (bid - 24) * 16; }
  for (int rep = 0; rep < REP_PACK; ++rep) {
    const float* sp = src + (size_t)r0 * nc;
#pragma unroll
    for (int i = 0; i < 16; ++i) {
      int fi = (i * 256 + t) * 4;
      *reinterpret_cast<float4*>(&ls[fi]) = *reinterpret_cast<const float4*>(sp + fi);
    }
    __syncthreads();
    if (nc == 256) {
      int kc0 = r0 >> 5;
#pragma unroll
      for (int f = 0; f < 8; ++f) {
        int fid = f * 256 + t;
        int kcl = fid >> 10, nt = (fid >> 6) & 15, ln = fid & 63;
        int n = nt * 16 + (ln & 15);
        int rb = kcl * 32 + (ln >> 4) * 8;
        u16x8 v;
#pragma unroll
        for (int e = 0; e < 8; ++e) v[e] = f2bf(ls[(rb + e) * 256 + n]);
        *reinterpret_cast<u16x8*>(
            dst + ((size_t)base8 + (size_t)(nt * KC + kc0 + kcl) * 64 + ln) * 8) = v;
      }
    } else {
      int kc = r0 >> 5, half = (r0 & 16) ? 32 : 0;
#pragma unroll
      for (int f = 0; f < 8; ++f) {
        int fid = f * 256 + t;
        int nt = fid >> 5, lnh = fid & 31;
        int ln = lnh + half;
        int n = nt * 16 + (ln & 15);
        int rb = ((ln >> 4) & 1) * 8;
        u16x8 v;
#pragma unroll
        for (int e = 0; e < 8; ++e) v[e] = f2bf(ls[(rb + e) * 1024 + n]);
        *reinterpret_cast<u16x8*>(
            dst + ((size_t)base8 + (size_t)(nt * 8 + kc) * 64 + ln) * 8) = v;
      }
    }
    __syncthreads();
  }
}

// ---------------------------------------------------------------------------
__global__ __launch_bounds__(256) void k2_fused(
    const float* __restrict__ text, const float* __restrict__ vis,
    const unsigned char* __restrict__ mask,
    const float* __restrict__ ref_w, const float* __restrict__ ref_b,
    const float* __restrict__ off_w, const float* __restrict__ off_b,
    const float* __restrict__ aw_w, const float* __restrict__ aw_b,
    const float* __restrict__ val_w, const float* __restrict__ val_b,
    float* __restrict__ ctx) {
  __shared__ float text_s[256];
  __shared__ float ref_s[6];
  __shared__ float off_s[192];
  __shared__ float aw_s[96];
  __shared__ float agg_s[8][260];
  __shared__ float csum_s[8];
  const int tid = threadIdx.x;
  const int bq = blockIdx.x;        // b*64 + q
  const int b = bq >> 6;
  const int h = tid >> 5, d = tid & 31;
  const unsigned char* maskb = mask + (size_t)b * S_TOT;
  const int Wl_[3] = {96, 48, 24};
  const int st_[3] = {0, 9216, 11520};

  for (int rep = 0; rep < REP_K2; ++rep) {
    text_s[tid] = text[(size_t)bq * 256 + tid];
    __syncthreads();

    for (int o = tid; o < 294; o += 256) {
      const float* wp; float a; int col, nc;
      if (o < 6)        { wp = ref_w; col = o;       nc = 6;   a = ref_b[col]; }
      else if (o < 198) { wp = off_w; col = o - 6;   nc = 192; a = off_b[col]; }
      else              { wp = aw_w;  col = o - 198; nc = 96;  a = aw_b[col]; }
      for (int k = 0; k < 256; ++k) a += text_s[k] * wp[(size_t)k * nc + col];
      if (o < 6)        ref_s[col] = 1.f / (1.f + expf(-a));
      else if (o < 198) off_s[col] = a;
      else              aw_s[col]  = a;
    }
    __syncthreads();
    if (tid < 8) {
      float mx = -3.4e38f;
      for (int j = 0; j < 12; ++j) mx = fmaxf(mx, aw_s[tid * 12 + j]);
      float e[12]; float s = 0.f;
      for (int j = 0; j < 12; ++j) { e[j] = expf(aw_s[tid * 12 + j] - mx); s += e[j]; }
      float inv = 1.f / s;
      for (int j = 0; j < 12; ++j) aw_s[tid * 12 + j] = e[j] * inv;
    }
    __syncthreads();

    float agg[8] = {0.f, 0.f, 0.f, 0.f, 0.f, 0.f, 0.f, 0.f};
    float csum = 0.f;
#pragma unroll
    for (int l = 0; l < 3; ++l) {
      const int Wl = Wl_[l], Hl = Wl_[l], st = st_[l];
      const float Wf = (float)Wl, Hf = (float)Hl;
      const float rx = ref_s[l * 2 + 0], ry = ref_s[l * 2 + 1];
#pragma unroll
      for (int p = 0; p < 4; ++p) {
        const int ip = (h * 3 + l) * 4 + p;
        const float ox = off_s[ip * 2 + 0], oy = off_s[ip * 2 + 1];
        const float aww = aw_s[ip];
        const float x = (rx + ox / Wf) * Wf - 0.5f;
        const float y = (ry + oy / Hf) * Hf - 0.5f;
        const float x0f = floorf(x), y0f = floorf(y);
        const float fx = x - x0f, fy = y - y0f;
        const int ix0 = (int)x0f, iy0 = (int)y0f;
        const bool xv0 = (ix0 >= 0) && (ix0 < Wl);
        const bool xv1 = (ix0 + 1 >= 0) && (ix0 + 1 < Wl);
        const bool yv0 = (iy0 >= 0) && (iy0 < Hl);
        const bool yv1 = (iy0 + 1 >= 0) && (iy0 + 1 < Hl);
        const float w00 = (yv0 && xv0) ? aww * (1.f - fx) * (1.f - fy) : 0.f;
        const float w10 = (yv0 && xv1) ? aww * fx * (1.f - fy) : 0.f;
        const float w01 = (yv1 && xv0) ? aww * (1.f - fx) * fy : 0.f;
        const float w11 = (yv1 && xv1) ? aww * fx * fy : 0.f;

        auto corner = [&](int iy, int ix, float cw) {
          if (cw != 0.f) {
            int s = st + iy * Wl + ix;
            if (!maskb[s]) {
              const float* rp = vis + ((size_t)(b * S_TOT + s)) * 256 + d * 8;
              float4 r0 = *reinterpret_cast<const float4*>(rp);
              float4 r1 = *reinterpret_cast<const float4*>(rp + 4);
              agg[0] += cw * r0.x; agg[1] += cw * r0.y;
              agg[2] += cw * r0.z; agg[3] += cw * r0.w;
              agg[4] += cw * r1.x; agg[5] += cw * r1.y;
              agg[6] += cw * r1.z; agg[7] += cw * r1.w;
              csum += cw;
            }
          }
        };
        corner(iy0,     ix0,     w00);
        corner(iy0,     ix0 + 1, w10);
        corner(iy0 + 1, ix0,     w01);
        corner(iy0 + 1, ix0 + 1, w11);
      }
    }
#pragma unroll
    for (int j = 0; j < 8; ++j) agg_s[h][d * 8 + j] = agg[j];
    if (d == 0) csum_s[h] = csum;
    __syncthreads();

    float a = csum_s[h] * val_b[tid];
    for (int k = 0; k < 256; k += 4) {
      a += agg_s[h][k + 0] * val_w[(size_t)(k + 0) * 256 + tid];
      a += agg_s[h][k + 1] * val_w[(size_t)(k + 1) * 256 + tid];
      a += agg_s[h][k + 2] * val_w[(size_t)(k + 2) * 256 + tid];
      a += agg_s[h][k + 3] * val_w[(size_t)(k + 3) * 256 + tid];
    }
    ctx[(size_t)bq * 256 + tid] = a;   // tid == h*32 + d
    __syncthreads();
  }
}

// ---------------------------------------------------------------------------
__device__ __forceinline__ int swz(int row, int bytecol, int rowbytes) {
  return (row * rowbytes + bytecol) ^ ((row & 7) << 4);
}

__global__ __launch_bounds__(1024) void k3_mfma(
    const float* __restrict__ ctx, const float* __restrict__ text,
    const u16* __restrict__ pk,
    const float* __restrict__ proj_b, const float* __restrict__ out_b,
    const float* __restrict__ n1_g, const float* __restrict__ n1_b,
    const float* __restrict__ f1_b, const float* __restrict__ f2_b,
    const float* __restrict__ n2_g, const float* __restrict__ n2_b,
    float* __restrict__ outp) {
  __shared__ u16 aA[16 * 256];
  __shared__ u16 aY[16 * 256];
  __shared__ u16 aH[16 * 1024];
  __shared__ float fb[16 * 256];

  const int tid = threadIdx.x;
  const int lane = tid & 63, wv = tid >> 6;       // wv 0..15
  const int l15 = lane & 15, lg = lane >> 4;
  const size_t r0 = (size_t)blockIdx.x * 16;
  const f32x4 z4 = {0.f, 0.f, 0.f, 0.f};

  for (int rep = 0; rep < REP_K3; ++rep) {
    // ---- stage ctx -> aA ----
    {
      int row = wv, c0 = lane * 4;
      const float* src = ctx + (r0 + row) * 256 + c0;
      u16x4 v;
#pragma unroll
      for (int j = 0; j < 4; ++j) v[j] = f2bf(src[j]);
      *reinterpret_cast<u16x4*>(reinterpret_cast<char*>(aA) + swz(row, c0 * 2, 512)) = v;
    }
    __syncthreads();

    // ---- proj ----
    {
      f32x4 acc = z4;
#pragma unroll
      for (int half = 0; half < 2; ++half) {
        bf16x8 b4[4];
#pragma unroll
        for (int i = 0; i < 4; ++i)
          b4[i] = *reinterpret_cast<const bf16x8*>(pk + ((wv * 8 + half * 4 + i) * 64 + lane) * 8);
#pragma unroll
        for (int i = 0; i < 4; ++i) {
          int kc = half * 4 + i;
          bf16x8 a = *reinterpret_cast<const bf16x8*>(
              reinterpret_cast<const char*>(aA) + swz(l15, kc * 64 + lg * 16, 512));
          acc = __builtin_amdgcn_mfma_f32_16x16x32_bf16(a, b4[i], acc, 0, 0, 0);
        }
      }
      int col = wv * 16 + l15;
      float bias = proj_b[col];
#pragma unroll
      for (int r = 0; r < 4; ++r) {
        int m = lg * 4 + r;
        *reinterpret_cast<u16*>(reinterpret_cast<char*>(aY) + swz(m, col * 2, 512)) =
            f2bf(acc[r] + bias);
      }
    }
    __syncthreads();

    // ---- out ----
    {
      const u16* pko = pk + 65536;
      f32x4 acc = z4;
#pragma unroll
      for (int half = 0; half < 2; ++half) {
        bf16x8 b4[4];
#pragma unroll
        for (int i = 0; i < 4; ++i)
          b4[i] = *reinterpret_cast<const bf16x8*>(pko + ((wv * 8 + half * 4 + i) * 64 + lane) * 8);
#pragma unroll
        for (int i = 0; i < 4; ++i) {
          int kc = half * 4 + i;
          bf16x8 a = *reinterpret_cast<const bf16x8*>(
              reinterpret_cast<const char*>(aY) + swz(l15, kc * 64 + lg * 16, 512));
          acc = __builtin_amdgcn_mfma_f32_16x16x32_bf16(a, b4[i], acc, 0, 0, 0);
        }
      }
      int col = wv * 16 + l15;
      float bias = out_b[col];
#pragma unroll
      for (int r = 0; r < 4; ++r) {
        int m = lg * 4 + r;
        fb[m * 256 + col] = acc[r] + bias + text[(r0 + m) * 256 + col];
      }
    }
    __syncthreads();

    // ---- LN1 ----
    {
      int row = wv;
      float s = 0.f;
#pragma unroll
      for (int j = 0; j < 4; ++j) s += fb[row * 256 + lane + j * 64];
#pragma unroll
      for (int o = 1; o < 64; o <<= 1) s += __shfl_xor(s, o, 64);
      float mu = s * 0.00390625f;
      float vs = 0.f;
#pragma unroll
      for (int j = 0; j < 4; ++j) {
        float dd = fb[row * 256 + lane + j * 64] - mu; vs += dd * dd;
      }
#pragma unroll
      for (int o = 1; o < 64; o <<= 1) vs += __shfl_xor(vs, o, 64);
      float rs = rsqrtf(vs * 0.00390625f + 1e-5f);
#pragma unroll
      for (int j = 0; j < 4; ++j) {
        int col = lane + j * 64;
        float v = (fb[row * 256 + col] - mu) * rs * n1_g[col] + n1_b[col];
        fb[row * 256 + col] = v;
        *reinterpret_cast<u16*>(reinterpret_cast<char*>(aA) + swz(row, col * 2, 512)) = f2bf(v);
      }
    }
    __syncthreads();

    // ---- f1 ----
    {
      const u16* pkf1 = pk + 131072;
#pragma unroll
      for (int nt = 0; nt < 4; ++nt) {
        int ntg = wv * 4 + nt;
        f32x4 acc = z4;
#pragma unroll
        for (int half = 0; half < 2; ++half) {
          bf16x8 b4[4];
#pragma unroll
          for (int i = 0; i < 4; ++i)
            b4[i] = *reinterpret_cast<const bf16x8*>(pkf1 + ((ntg * 8 + half * 4 + i) * 64 + lane) * 8);
#pragma unroll
          for (int i = 0; i < 4; ++i) {
            int kc = half * 4 + i;
            bf16x8 a = *reinterpret_cast<const bf16x8*>(
                reinterpret_cast<const char*>(aA) + swz(l15, kc * 64 + lg * 16, 512));
            acc = __builtin_amdgcn_mfma_f32_16x16x32_bf16(a, b4[i], acc, 0, 0, 0);
          }
        }
        int col = ntg * 16 + l15;
        float bias = f1_b[col];
#pragma unroll
        for (int r = 0; r < 4; ++r) {
          int m = lg * 4 + r;
          *reinterpret_cast<u16*>(reinterpret_cast<char*>(aH) + swz(m, col * 2, 2048)) =
              f2bf(fmaxf(acc[r] + bias, 0.f));
        }
      }
    }
    __syncthreads();

    // ---- f2 ----
    {
      const u16* pkf2 = pk + 393216;
      f32x4 acc = z4;
#pragma unroll
      for (int c = 0; c < 8; ++c) {
        bf16x8 b4[4];
#pragma unroll
        for (int i = 0; i < 4; ++i)
          b4[i] = *reinterpret_cast<const bf16x8*>(pkf2 + ((wv * 32 + c * 4 + i) * 64 + lane) * 8);
#pragma unroll
        for (int i = 0; i < 4; ++i) {
          int kc = c * 4 + i;
          bf16x8 a = *reinterpret_cast<const bf16x8*>(
              reinterpret_cast<const char*>(aH) + swz(l15, kc * 64 + lg * 16, 2048));
          acc = __builtin_amdgcn_mfma_f32_16x16x32_bf16(a, b4[i], acc, 0, 0, 0);
        }
      }
      int col = wv * 16 + l15;
      float bias = f2_b[col];
#pragma unroll
      for (int r = 0; r < 4; ++r) {
        int m = lg * 4 + r;
        fb[m * 256 + col] = acc[r] + bias + fb[m * 256 + col];
      }
    }
    __syncthreads();

    // ---- LN2 -> out ----
    {
      int row = wv;
      float s = 0.f;
#pragma unroll
      for (int j = 0; j < 4; ++j) s += fb[row * 256 + lane + j * 64];
#pragma unroll
      for (int o = 1; o < 64; o <<= 1) s += __shfl_xor(s, o, 64);
      float mu = s * 0.00390625f;
      float vs = 0.f;
#pragma unroll
      for (int j = 0; j < 4; ++j) {
        float dd = fb[row * 256 + lane + j * 64] - mu; vs += dd * dd;
      }
#pragma unroll
      for (int o = 1; o < 64; o <<= 1) vs += __shfl_xor(vs, o, 64);
      float rs = rsqrtf(vs * 0.00390625f + 1e-5f);
#pragma unroll
      for (int j = 0; j < 4; ++j) {
        int col = lane + j * 64;
        outp[(r0 + row) * 256 + col] = (fb[row * 256 + col] - mu) * rs * n2_g[col] + n2_b[col];
      }
    }
    __syncthreads();
  }
}

// ---------------------------------------------------------------------------
extern "C" void kernel_launch(void* const* d_in, const int* in_sizes, int n_in,
                              void* d_out, int out_size, void* d_ws, size_t ws_size,
                              hipStream_t stream) {
  const float* text  = (const float*)d_in[0];
  const float* vis   = (const float*)d_in[1];
  const unsigned char* mask = (const unsigned char*)d_in[4];
  const float* ref_w = (const float*)d_in[5];
  const float* ref_b = (const float*)d_in[6];
  const float* off_w = (const float*)d_in[7];
  const float* off_b = (const float*)d_in[8];
  const float* aw_w  = (const float*)d_in[9];
  const float* aw_b  = (const float*)d_in[10];
  const float* val_w = (const float*)d_in[11];
  const float* val_b = (const float*)d_in[12];
  const float* proj_w = (const float*)d_in[13];
  const float* proj_b = (const float*)d_in[14];
  const float* out_w = (const float*)d_in[15];
  const float* out_b = (const float*)d_in[16];
  const float* n1_g  = (const float*)d_in[17];
  const float* n1_b  = (const float*)d_in[18];
  const float* f1_w  = (const float*)d_in[19];
  const float* f1_b  = (const float*)d_in[20];
  const float* f2_w  = (const float*)d_in[21];
  const float* f2_b  = (const float*)d_in[22];
  const float* n2_g  = (const float*)d_in[23];
  const float* n2_b  = (const float*)d_in[24];
  float* outp = (float*)d_out;

  char* ws = (char*)d_ws;
  float* ctx = (float*)ws;                       // 1 MB
  u16* pk    = (u16*)(ws + (size_t)1024 * 1024); // 1.25 MB packed weights

  k_pack<<<40, 256, 0, stream>>>(proj_w, out_w, f1_w, f2_w, pk);
  k2_fused<<<1024, 256, 0, stream>>>(text, vis, mask, ref_w, ref_b, off_w, off_b,
                                     aw_w, aw_b, val_w, val_b, ctx);
  k3_mfma<<<64, 1024, 0, stream>>>(ctx, text, pk, proj_b, out_b,
                                   n1_g, n1_b, f1_b, f2_b, n2_g, n2_b, outp);
}

// Round 15
// 91.036 us; speedup vs baseline: 9.3529x; 9.3529x over previous
//
#include <hip/hip_runtime.h>

#define S_TOT 12096
typedef unsigned short u16;
typedef __attribute__((ext_vector_type(4))) unsigned short u16x4;
typedef __attribute__((ext_vector_type(8))) unsigned short u16x8;
typedef __attribute__((ext_vector_type(8))) short bf16x8;
typedef __attribute__((ext_vector_type(4))) float f32x4;

__device__ __forceinline__ u16 f2bf(float f) {
  union { float f; unsigned u; } v; v.f = f;
  unsigned r = v.u + 0x7FFFu + ((v.u >> 16) & 1u);  // round-nearest-even
  return (u16)(r >> 16);
}

// ---------------------------------------------------------------------------
// k_pack: blocks 0..39 = r13-proven LDS-staged pack of proj/out/f1/f2.
// blocks 40..77 = NEW: pack combined projection weights [ref|off|aw|0-pad]
// (256 x 304) into fragments at pk + 81920*8 (one u16x8 per thread).
// ---------------------------------------------------------------------------
__global__ __launch_bounds__(256) void k_pack(
    const float* __restrict__ pw, const float* __restrict__ ow,
    const float* __restrict__ f1w, const float* __restrict__ f2w,
    const float* __restrict__ rfw, const float* __restrict__ ofw,
    const float* __restrict__ awW,
    u16* __restrict__ dst) {
  const int t = threadIdx.x;
  const int bid = blockIdx.x;   // 0..77
  if (bid >= 40) {              // ---- projection-weight pack ----
    int t2 = (bid - 40) * 256 + t;        // 0..9727
    int ln = t2 & 63;
    int kc = (t2 >> 6) & 7;
    int nt = t2 >> 9;                     // 0..18
    int col = nt * 16 + (ln & 15);
    int k0 = kc * 32 + (ln >> 4) * 8;
    u16x8 v;
#pragma unroll
    for (int e = 0; e < 8; ++e) {
      int k = k0 + e;
      float val;
      if (col < 6)        val = rfw[k * 6 + col];
      else if (col < 198) val = ofw[k * 192 + (col - 6)];
      else if (col < 294) val = awW[k * 96 + (col - 198)];
      else                val = 0.f;
      v[e] = f2bf(val);
    }
    *reinterpret_cast<u16x8*>(dst + ((size_t)81920 + (size_t)(nt * 8 + kc) * 64 + ln) * 8) = v;
    return;
  }
  __shared__ float ls[16384];   // 64 KB tile
  const float* src; int nc, KC, base8, r0;
  if (bid < 4)       { src = pw;  nc = 256;  KC = 8;  base8 = 0;     r0 = bid * 64; }
  else if (bid < 8)  { src = ow;  nc = 256;  KC = 8;  base8 = 8192;  r0 = (bid - 4) * 64; }
  else if (bid < 24) { src = f2w; nc = 256;  KC = 32; base8 = 49152; r0 = (bid - 8) * 64; }
  else               { src = f1w; nc = 1024; KC = 8;  base8 = 16384; r0 = (bid - 24) * 16; }
  const float* sp = src + (size_t)r0 * nc;
#pragma unroll
  for (int i = 0; i < 16; ++i) {
    int fi = (i * 256 + t) * 4;
    *reinterpret_cast<float4*>(&ls[fi]) = *reinterpret_cast<const float4*>(sp + fi);
  }
  __syncthreads();
  if (nc == 256) {
    int kc0 = r0 >> 5;
#pragma unroll
    for (int f = 0; f < 8; ++f) {
      int fid = f * 256 + t;
      int kcl = fid >> 10, nt = (fid >> 6) & 15, ln = fid & 63;
      int n = nt * 16 + (ln & 15);
      int rb = kcl * 32 + (ln >> 4) * 8;
      u16x8 v;
#pragma unroll
      for (int e = 0; e < 8; ++e) v[e] = f2bf(ls[(rb + e) * 256 + n]);
      *reinterpret_cast<u16x8*>(
          dst + ((size_t)base8 + (size_t)(nt * KC + kc0 + kcl) * 64 + ln) * 8) = v;
    }
  } else {
    int kc = r0 >> 5, half = (r0 & 16) ? 32 : 0;
#pragma unroll
    for (int f = 0; f < 8; ++f) {
      int fid = f * 256 + t;
      int nt = fid >> 5, lnh = fid & 31;
      int ln = lnh + half;
      int n = nt * 16 + (ln & 15);
      int rb = ((ln >> 4) & 1) * 8;
      u16x8 v;
#pragma unroll
      for (int e = 0; e < 8; ++e) v[e] = f2bf(ls[(rb + e) * 1024 + n]);
      *reinterpret_cast<u16x8*>(
          dst + ((size_t)base8 + (size_t)(nt * 8 + kc) * 64 + ln) * 8) = v;
    }
  }
}

// ---------------------------------------------------------------------------
__device__ __forceinline__ int swz(int row, int bytecol, int rowbytes) {
  return (row * rowbytes + bytecol) ^ ((row & 7) << 4);
}

// ---------------------------------------------------------------------------
// k_proj: P[1024 x 304] = text @ [ref_w|off_w|aw_w|0] + bias (raw, fp32).
// 64 blocks x 16 rows, 16 waves; waves 0..2 handle a second n-tile (16..18).
// Same proven MFMA fragment path as k3.
// ---------------------------------------------------------------------------
__global__ __launch_bounds__(1024) void k_proj(
    const float* __restrict__ text, const u16* __restrict__ pkp,
    const float* __restrict__ ref_b, const float* __restrict__ off_b,
    const float* __restrict__ aw_b, float* __restrict__ P) {
  __shared__ u16 aT[16 * 256];
  const int tid = threadIdx.x;
  const int lane = tid & 63, wv = tid >> 6;
  const int l15 = lane & 15, lg = lane >> 4;
  const size_t r0 = (size_t)blockIdx.x * 16;
  const f32x4 z4 = {0.f, 0.f, 0.f, 0.f};
  {
    int row = wv, c0 = lane * 4;
    const float* src = text + (r0 + row) * 256 + c0;
    u16x4 v;
#pragma unroll
    for (int j = 0; j < 4; ++j) v[j] = f2bf(src[j]);
    *reinterpret_cast<u16x4*>(reinterpret_cast<char*>(aT) + swz(row, c0 * 2, 512)) = v;
  }
  __syncthreads();
  const int nrep = (wv < 3) ? 2 : 1;
  for (int rep = 0; rep < nrep; ++rep) {
    int nt = wv + rep * 16;     // 0..18
    f32x4 acc = z4;
#pragma unroll
    for (int half = 0; half < 2; ++half) {
      bf16x8 b4[4];
#pragma unroll
      for (int i = 0; i < 4; ++i)
        b4[i] = *reinterpret_cast<const bf16x8*>(pkp + ((size_t)(nt * 8 + half * 4 + i) * 64 + lane) * 8);
#pragma unroll
      for (int i = 0; i < 4; ++i) {
        int kc = half * 4 + i;
        bf16x8 a = *reinterpret_cast<const bf16x8*>(
            reinterpret_cast<const char*>(aT) + swz(l15, kc * 64 + lg * 16, 512));
        acc = __builtin_amdgcn_mfma_f32_16x16x32_bf16(a, b4[i], acc, 0, 0, 0);
      }
    }
    int col = nt * 16 + l15;
    float bias = (col < 6) ? ref_b[col]
               : (col < 198) ? off_b[col - 6]
               : (col < 294) ? aw_b[col - 198] : 0.f;
#pragma unroll
    for (int r = 0; r < 4; ++r) {
      int m = lg * 4 + r;
      P[(r0 + m) * 304 + col] = acc[r] + bias;
    }
  }
}

// ---------------------------------------------------------------------------
// K2 v2: reads precomputed projections P; branchless clamped 4-corner gather;
// per-head aggregate + GEMV vs val_w (unchanged math).
// ---------------------------------------------------------------------------
__global__ __launch_bounds__(256) void k2_fused(
    const float* __restrict__ P, const float* __restrict__ vis,
    const unsigned char* __restrict__ mask,
    const float* __restrict__ val_w, const float* __restrict__ val_b,
    float* __restrict__ ctx) {
  __shared__ float p_s[304];
  __shared__ float ref_s[6];
  __shared__ float aw_s[96];
  __shared__ float agg_s[8][260];
  __shared__ float csum_s[8];
  const int tid = threadIdx.x;
  const int bq = blockIdx.x;        // b*64 + q
  const int b = bq >> 6;
  p_s[tid] = P[(size_t)bq * 304 + tid];
  if (tid < 48) p_s[256 + tid] = P[(size_t)bq * 304 + 256 + tid];
  __syncthreads();
  if (tid < 6) ref_s[tid] = 1.f / (1.f + expf(-p_s[tid]));
  if (tid >= 8 && tid < 16) {  // softmax per head (threads 8..15 -> heads 0..7)
    int hh = tid - 8;
    float mx = -3.4e38f;
    for (int j = 0; j < 12; ++j) mx = fmaxf(mx, p_s[198 + hh * 12 + j]);
    float e[12]; float s = 0.f;
    for (int j = 0; j < 12; ++j) { e[j] = expf(p_s[198 + hh * 12 + j] - mx); s += e[j]; }
    float inv = 1.f / s;
    for (int j = 0; j < 12; ++j) aw_s[hh * 12 + j] = e[j] * inv;
  }
  __syncthreads();

  const int h = tid >> 5, d = tid & 31;
  float agg[8] = {0.f, 0.f, 0.f, 0.f, 0.f, 0.f, 0.f, 0.f};
  float csum = 0.f;
  const unsigned char* maskb = mask + (size_t)b * S_TOT;
  const float* visb = vis + (size_t)b * S_TOT * 256 + d * 8;
  const int Wl_[3] = {96, 48, 24};
  const int st_[3] = {0, 9216, 11520};

#pragma unroll
  for (int l = 0; l < 3; ++l) {
    const int Wl = Wl_[l], Hl = Wl_[l], st = st_[l];
    const float Wf = (float)Wl, Hf = (float)Hl;
    const float rx = ref_s[l * 2 + 0], ry = ref_s[l * 2 + 1];
#pragma unroll
    for (int p = 0; p < 4; ++p) {
      const int ip = (h * 3 + l) * 4 + p;
      const float ox = p_s[6 + ip * 2 + 0], oy = p_s[6 + ip * 2 + 1];
      const float aww = aw_s[ip];
      const float x = (rx + ox / Wf) * Wf - 0.5f;
      const float y = (ry + oy / Hf) * Hf - 0.5f;
      const float x0f = floorf(x), y0f = floorf(y);
      const float fx = x - x0f, fy = y - y0f;
      const int ix0 = (int)x0f, iy0 = (int)y0f;
      const bool xv0 = (unsigned)ix0 < (unsigned)Wl;
      const bool xv1 = (unsigned)(ix0 + 1) < (unsigned)Wl;
      const bool yv0 = (unsigned)iy0 < (unsigned)Hl;
      const bool yv1 = (unsigned)(iy0 + 1) < (unsigned)Hl;
      const int cx0 = min(max(ix0, 0), Wl - 1), cx1 = min(max(ix0 + 1, 0), Wl - 1);
      const int cy0 = min(max(iy0, 0), Hl - 1), cy1 = min(max(iy0 + 1, 0), Hl - 1);
      const int s00 = st + cy0 * Wl + cx0, s10 = st + cy0 * Wl + cx1;
      const int s01 = st + cy1 * Wl + cx0, s11 = st + cy1 * Wl + cx1;
      float w00 = (yv0 && xv0 && !maskb[s00]) ? aww * (1.f - fx) * (1.f - fy) : 0.f;
      float w10 = (yv0 && xv1 && !maskb[s10]) ? aww * fx * (1.f - fy) : 0.f;
      float w01 = (yv1 && xv0 && !maskb[s01]) ? aww * (1.f - fx) * fy : 0.f;
      float w11 = (yv1 && xv1 && !maskb[s11]) ? aww * fx * fy : 0.f;
      csum += w00 + w10 + w01 + w11;
      const float* p00 = visb + (size_t)s00 * 256;
      const float* p10 = visb + (size_t)s10 * 256;
      const float* p01 = visb + (size_t)s01 * 256;
      const float* p11 = visb + (size_t)s11 * 256;
      float4 a0 = *reinterpret_cast<const float4*>(p00);
      float4 a1 = *reinterpret_cast<const float4*>(p00 + 4);
      float4 b0 = *reinterpret_cast<const float4*>(p10);
      float4 b1 = *reinterpret_cast<const float4*>(p10 + 4);
      float4 c0 = *reinterpret_cast<const float4*>(p01);
      float4 c1 = *reinterpret_cast<const float4*>(p01 + 4);
      float4 e0 = *reinterpret_cast<const float4*>(p11);
      float4 e1 = *reinterpret_cast<const float4*>(p11 + 4);
      agg[0] += w00 * a0.x + w10 * b0.x + w01 * c0.x + w11 * e0.x;
      agg[1] += w00 * a0.y + w10 * b0.y + w01 * c0.y + w11 * e0.y;
      agg[2] += w00 * a0.z + w10 * b0.z + w01 * c0.z + w11 * e0.z;
      agg[3] += w00 * a0.w + w10 * b0.w + w01 * c0.w + w11 * e0.w;
      agg[4] += w00 * a1.x + w10 * b1.x + w01 * c1.x + w11 * e1.x;
      agg[5] += w00 * a1.y + w10 * b1.y + w01 * c1.y + w11 * e1.y;
      agg[6] += w00 * a1.z + w10 * b1.z + w01 * c1.z + w11 * e1.z;
      agg[7] += w00 * a1.w + w10 * b1.w + w01 * c1.w + w11 * e1.w;
    }
  }
#pragma unroll
  for (int j = 0; j < 8; ++j) agg_s[h][d * 8 + j] = agg[j];
  if (d == 0) csum_s[h] = csum;
  __syncthreads();

  float a = csum_s[h] * val_b[tid];
  for (int k = 0; k < 256; k += 4) {
    a += agg_s[h][k + 0] * val_w[(size_t)(k + 0) * 256 + tid];
    a += agg_s[h][k + 1] * val_w[(size_t)(k + 1) * 256 + tid];
    a += agg_s[h][k + 2] * val_w[(size_t)(k + 2) * 256 + tid];
    a += agg_s[h][k + 3] * val_w[(size_t)(k + 3) * 256 + tid];
  }
  ctx[(size_t)bq * 256 + tid] = a;   // tid == h*32 + d
}

// ---------------------------------------------------------------------------
// K3 v4: MFMA tail (r12-proven, byte-identical). 16 waves/block, 64 blocks.
// ---------------------------------------------------------------------------
__global__ __launch_bounds__(1024) void k3_mfma(
    const float* __restrict__ ctx, const float* __restrict__ text,
    const u16* __restrict__ pk,
    const float* __restrict__ proj_b, const float* __restrict__ out_b,
    const float* __restrict__ n1_g, const float* __restrict__ n1_b,
    const float* __restrict__ f1_b, const float* __restrict__ f2_b,
    const float* __restrict__ n2_g, const float* __restrict__ n2_b,
    float* __restrict__ outp) {
  __shared__ u16 aA[16 * 256];
  __shared__ u16 aY[16 * 256];
  __shared__ u16 aH[16 * 1024];
  __shared__ float fb[16 * 256];

  const int tid = threadIdx.x;
  const int lane = tid & 63, wv = tid >> 6;
  const int l15 = lane & 15, lg = lane >> 4;
  const size_t r0 = (size_t)blockIdx.x * 16;
  const f32x4 z4 = {0.f, 0.f, 0.f, 0.f};

  {
    int row = wv, c0 = lane * 4;
    const float* src = ctx + (r0 + row) * 256 + c0;
    u16x4 v;
#pragma unroll
    for (int j = 0; j < 4; ++j) v[j] = f2bf(src[j]);
    *reinterpret_cast<u16x4*>(reinterpret_cast<char*>(aA) + swz(row, c0 * 2, 512)) = v;
  }
  __syncthreads();

  {
    f32x4 acc = z4;
#pragma unroll
    for (int half = 0; half < 2; ++half) {
      bf16x8 b4[4];
#pragma unroll
      for (int i = 0; i < 4; ++i)
        b4[i] = *reinterpret_cast<const bf16x8*>(pk + ((wv * 8 + half * 4 + i) * 64 + lane) * 8);
#pragma unroll
      for (int i = 0; i < 4; ++i) {
        int kc = half * 4 + i;
        bf16x8 a = *reinterpret_cast<const bf16x8*>(
            reinterpret_cast<const char*>(aA) + swz(l15, kc * 64 + lg * 16, 512));
        acc = __builtin_amdgcn_mfma_f32_16x16x32_bf16(a, b4[i], acc, 0, 0, 0);
      }
    }
    int col = wv * 16 + l15;
    float bias = proj_b[col];
#pragma unroll
    for (int r = 0; r < 4; ++r) {
      int m = lg * 4 + r;
      *reinterpret_cast<u16*>(reinterpret_cast<char*>(aY) + swz(m, col * 2, 512)) =
          f2bf(acc[r] + bias);
    }
  }
  __syncthreads();

  {
    const u16* pko = pk + 65536;
    f32x4 acc = z4;
#pragma unroll
    for (int half = 0; half < 2; ++half) {
      bf16x8 b4[4];
#pragma unroll
      for (int i = 0; i < 4; ++i)
        b4[i] = *reinterpret_cast<const bf16x8*>(pko + ((wv * 8 + half * 4 + i) * 64 + lane) * 8);
#pragma unroll
      for (int i = 0; i < 4; ++i) {
        int kc = half * 4 + i;
        bf16x8 a = *reinterpret_cast<const bf16x8*>(
            reinterpret_cast<const char*>(aY) + swz(l15, kc * 64 + lg * 16, 512));
        acc = __builtin_amdgcn_mfma_f32_16x16x32_bf16(a, b4[i], acc, 0, 0, 0);
      }
    }
    int col = wv * 16 + l15;
    float bias = out_b[col];
#pragma unroll
    for (int r = 0; r < 4; ++r) {
      int m = lg * 4 + r;
      fb[m * 256 + col] = acc[r] + bias + text[(r0 + m) * 256 + col];
    }
  }
  __syncthreads();

  {
    int row = wv;
    float s = 0.f;
#pragma unroll
    for (int j = 0; j < 4; ++j) s += fb[row * 256 + lane + j * 64];
#pragma unroll
    for (int o = 1; o < 64; o <<= 1) s += __shfl_xor(s, o, 64);
    float mu = s * 0.00390625f;
    float vs = 0.f;
#pragma unroll
    for (int j = 0; j < 4; ++j) {
      float dd = fb[row * 256 + lane + j * 64] - mu; vs += dd * dd;
    }
#pragma unroll
    for (int o = 1; o < 64; o <<= 1) vs += __shfl_xor(vs, o, 64);
    float rs = rsqrtf(vs * 0.00390625f + 1e-5f);
#pragma unroll
    for (int j = 0; j < 4; ++j) {
      int col = lane + j * 64;
      float v = (fb[row * 256 + col] - mu) * rs * n1_g[col] + n1_b[col];
      fb[row * 256 + col] = v;
      *reinterpret_cast<u16*>(reinterpret_cast<char*>(aA) + swz(row, col * 2, 512)) = f2bf(v);
    }
  }
  __syncthreads();

  {
    const u16* pkf1 = pk + 131072;
#pragma unroll
    for (int nt = 0; nt < 4; ++nt) {
      int ntg = wv * 4 + nt;
      f32x4 acc = z4;
#pragma unroll
      for (int half = 0; half < 2; ++half) {
        bf16x8 b4[4];
#pragma unroll
        for (int i = 0; i < 4; ++i)
          b4[i] = *reinterpret_cast<const bf16x8*>(pkf1 + ((ntg * 8 + half * 4 + i) * 64 + lane) * 8);
#pragma unroll
        for (int i = 0; i < 4; ++i) {
          int kc = half * 4 + i;
          bf16x8 a = *reinterpret_cast<const bf16x8*>(
              reinterpret_cast<const char*>(aA) + swz(l15, kc * 64 + lg * 16, 512));
          acc = __builtin_amdgcn_mfma_f32_16x16x32_bf16(a, b4[i], acc, 0, 0, 0);
        }
      }
      int col = ntg * 16 + l15;
      float bias = f1_b[col];
#pragma unroll
      for (int r = 0; r < 4; ++r) {
        int m = lg * 4 + r;
        *reinterpret_cast<u16*>(reinterpret_cast<char*>(aH) + swz(m, col * 2, 2048)) =
            f2bf(fmaxf(acc[r] + bias, 0.f));
      }
    }
  }
  __syncthreads();

  {
    const u16* pkf2 = pk + 393216;
    f32x4 acc = z4;
#pragma unroll
    for (int c = 0; c < 8; ++c) {
      bf16x8 b4[4];
#pragma unroll
      for (int i = 0; i < 4; ++i)
        b4[i] = *reinterpret_cast<const bf16x8*>(pkf2 + ((wv * 32 + c * 4 + i) * 64 + lane) * 8);
#pragma unroll
      for (int i = 0; i < 4; ++i) {
        int kc = c * 4 + i;
        bf16x8 a = *reinterpret_cast<const bf16x8*>(
            reinterpret_cast<const char*>(aH) + swz(l15, kc * 64 + lg * 16, 2048));
        acc = __builtin_amdgcn_mfma_f32_16x16x32_bf16(a, b4[i], acc, 0, 0, 0);
      }
    }
    int col = wv * 16 + l15;
    float bias = f2_b[col];
#pragma unroll
    for (int r = 0; r < 4; ++r) {
      int m = lg * 4 + r;
      fb[m * 256 + col] = acc[r] + bias + fb[m * 256 + col];
    }
  }
  __syncthreads();

  {
    int row = wv;
    float s = 0.f;
#pragma unroll
    for (int j = 0; j < 4; ++j) s += fb[row * 256 + lane + j * 64];
#pragma unroll
    for (int o = 1; o < 64; o <<= 1) s += __shfl_xor(s, o, 64);
    float mu = s * 0.00390625f;
    float vs = 0.f;
#pragma unroll
    for (int j = 0; j < 4; ++j) {
      float dd = fb[row * 256 + lane + j * 64] - mu; vs += dd * dd;
    }
#pragma unroll
    for (int o = 1; o < 64; o <<= 1) vs += __shfl_xor(vs, o, 64);
    float rs = rsqrtf(vs * 0.00390625f + 1e-5f);
#pragma unroll
    for (int j = 0; j < 4; ++j) {
      int col = lane + j * 64;
      outp[(r0 + row) * 256 + col] = (fb[row * 256 + col] - mu) * rs * n2_g[col] + n2_b[col];
    }
  }
}

// ---------------------------------------------------------------------------
extern "C" void kernel_launch(void* const* d_in, const int* in_sizes, int n_in,
                              void* d_out, int out_size, void* d_ws, size_t ws_size,
                              hipStream_t stream) {
  const float* text  = (const float*)d_in[0];
  const float* vis   = (const float*)d_in[1];
  const unsigned char* mask = (const unsigned char*)d_in[4];
  const float* ref_w = (const float*)d_in[5];
  const float* ref_b = (const float*)d_in[6];
  const float* off_w = (const float*)d_in[7];
  const float* off_b = (const float*)d_in[8];
  const float* aw_w  = (const float*)d_in[9];
  const float* aw_b  = (const float*)d_in[10];
  const float* val_w = (const float*)d_in[11];
  const float* val_b = (const float*)d_in[12];
  const float* proj_w = (const float*)d_in[13];
  const float* proj_b = (const float*)d_in[14];
  const float* out_w = (const float*)d_in[15];
  const float* out_b = (const float*)d_in[16];
  const float* n1_g  = (const float*)d_in[17];
  const float* n1_b  = (const float*)d_in[18];
  const float* f1_w  = (const float*)d_in[19];
  const float* f1_b  = (const float*)d_in[20];
  const float* f2_w  = (const float*)d_in[21];
  const float* f2_b  = (const float*)d_in[22];
  const float* n2_g  = (const float*)d_in[23];
  const float* n2_b  = (const float*)d_in[24];
  float* outp = (float*)d_out;

  char* ws = (char*)d_ws;
  float* ctx = (float*)ws;                            // 1.0 MB
  u16* pk    = (u16*)(ws + (size_t)1024 * 1024);      // 1.4 MB packed weights
  u16* pkp   = pk + (size_t)81920 * 8;                // proj-weight fragments
  float* P   = (float*)(ws + (size_t)2560 * 1024);    // 1.22 MB projections

  k_pack<<<78, 256, 0, stream>>>(proj_w, out_w, f1_w, f2_w, ref_w, off_w, aw_w, pk);
  k_proj<<<64, 1024, 0, stream>>>(text, pkp, ref_b, off_b, aw_b, P);
  k2_fused<<<1024, 256, 0, stream>>>(P, vis, mask, val_w, val_b, ctx);
  k3_mfma<<<64, 1024, 0, stream>>>(ctx, text, pk, proj_b, out_b,
                                   n1_g, n1_b, f1_b, f2_b, n2_g, n2_b, outp);
}

// Round 16
// 84.887 us; speedup vs baseline: 10.0305x; 1.0724x over previous
//
#include <hip/hip_runtime.h>

#define S_TOT 12096
typedef unsigned short u16;
typedef __attribute__((ext_vector_type(4))) unsigned short u16x4;
typedef __attribute__((ext_vector_type(8))) unsigned short u16x8;
typedef __attribute__((ext_vector_type(8))) short bf16x8;
typedef __attribute__((ext_vector_type(4))) float f32x4;

__device__ __forceinline__ u16 f2bf(float f) {
  union { float f; unsigned u; } v; v.f = f;
  unsigned r = v.u + 0x7FFFu + ((v.u >> 16) & 1u);  // round-nearest-even
  return (u16)(r >> 16);
}

// ---------------------------------------------------------------------------
// k_pack: blocks 0..39 big-weight pack (r13-proven); 40..77 proj-weight pack.
// ---------------------------------------------------------------------------
__global__ __launch_bounds__(256) void k_pack(
    const float* __restrict__ pw, const float* __restrict__ ow,
    const float* __restrict__ f1w, const float* __restrict__ f2w,
    const float* __restrict__ rfw, const float* __restrict__ ofw,
    const float* __restrict__ awW,
    u16* __restrict__ dst) {
  const int t = threadIdx.x;
  const int bid = blockIdx.x;   // 0..77
  if (bid >= 40) {              // ---- projection-weight pack ----
    int t2 = (bid - 40) * 256 + t;        // 0..9727
    int ln = t2 & 63;
    int kc = (t2 >> 6) & 7;
    int nt = t2 >> 9;                     // 0..18
    int col = nt * 16 + (ln & 15);
    int k0 = kc * 32 + (ln >> 4) * 8;
    u16x8 v;
#pragma unroll
    for (int e = 0; e < 8; ++e) {
      int k = k0 + e;
      float val;
      if (col < 6)        val = rfw[k * 6 + col];
      else if (col < 198) val = ofw[k * 192 + (col - 6)];
      else if (col < 294) val = awW[k * 96 + (col - 198)];
      else                val = 0.f;
      v[e] = f2bf(val);
    }
    *reinterpret_cast<u16x8*>(dst + ((size_t)81920 + (size_t)(nt * 8 + kc) * 64 + ln) * 8) = v;
    return;
  }
  __shared__ float ls[16384];   // 64 KB tile
  const float* src; int nc, KC, base8, r0;
  if (bid < 4)       { src = pw;  nc = 256;  KC = 8;  base8 = 0;     r0 = bid * 64; }
  else if (bid < 8)  { src = ow;  nc = 256;  KC = 8;  base8 = 8192;  r0 = (bid - 4) * 64; }
  else if (bid < 24) { src = f2w; nc = 256;  KC = 32; base8 = 49152; r0 = (bid - 8) * 64; }
  else               { src = f1w; nc = 1024; KC = 8;  base8 = 16384; r0 = (bid - 24) * 16; }
  const float* sp = src + (size_t)r0 * nc;
#pragma unroll
  for (int i = 0; i < 16; ++i) {
    int fi = (i * 256 + t) * 4;
    *reinterpret_cast<float4*>(&ls[fi]) = *reinterpret_cast<const float4*>(sp + fi);
  }
  __syncthreads();
  if (nc == 256) {
    int kc0 = r0 >> 5;
#pragma unroll
    for (int f = 0; f < 8; ++f) {
      int fid = f * 256 + t;
      int kcl = fid >> 10, nt = (fid >> 6) & 15, ln = fid & 63;
      int n = nt * 16 + (ln & 15);
      int rb = kcl * 32 + (ln >> 4) * 8;
      u16x8 v;
#pragma unroll
      for (int e = 0; e < 8; ++e) v[e] = f2bf(ls[(rb + e) * 256 + n]);
      *reinterpret_cast<u16x8*>(
          dst + ((size_t)base8 + (size_t)(nt * KC + kc0 + kcl) * 64 + ln) * 8) = v;
    }
  } else {
    int kc = r0 >> 5, half = (r0 & 16) ? 32 : 0;
#pragma unroll
    for (int f = 0; f < 8; ++f) {
      int fid = f * 256 + t;
      int nt = fid >> 5, lnh = fid & 31;
      int ln = lnh + half;
      int n = nt * 16 + (ln & 15);
      int rb = ((ln >> 4) & 1) * 8;
      u16x8 v;
#pragma unroll
      for (int e = 0; e < 8; ++e) v[e] = f2bf(ls[(rb + e) * 1024 + n]);
      *reinterpret_cast<u16x8*>(
          dst + ((size_t)base8 + (size_t)(nt * 8 + kc) * 64 + ln) * 8) = v;
    }
  }
}

// ---------------------------------------------------------------------------
__device__ __forceinline__ int swz(int row, int bytecol, int rowbytes) {
  return (row * rowbytes + bytecol) ^ ((row & 7) << 4);
}

// ---------------------------------------------------------------------------
// k_proj: P[1024 x 304] = text @ [ref_w|off_w|aw_w|0] + bias; ALSO zeroes ctx
// (k2 accumulates into ctx via atomicAdd this round).
// ---------------------------------------------------------------------------
__global__ __launch_bounds__(1024) void k_proj(
    const float* __restrict__ text, const u16* __restrict__ pkp,
    const float* __restrict__ ref_b, const float* __restrict__ off_b,
    const float* __restrict__ aw_b, float* __restrict__ P,
    float* __restrict__ ctx) {
  __shared__ u16 aT[16 * 256];
  const int tid = threadIdx.x;
  const int lane = tid & 63, wv = tid >> 6;
  const int l15 = lane & 15, lg = lane >> 4;
  const size_t r0 = (size_t)blockIdx.x * 16;
  const f32x4 z4 = {0.f, 0.f, 0.f, 0.f};
  {  // zero ctx: 64 blocks x 1024 threads x 4 floats = 262144
    int gt = blockIdx.x * 1024 + tid;
    float4 z = {0.f, 0.f, 0.f, 0.f};
    *reinterpret_cast<float4*>(ctx + (size_t)gt * 4) = z;
  }
  {
    int row = wv, c0 = lane * 4;
    const float* src = text + (r0 + row) * 256 + c0;
    u16x4 v;
#pragma unroll
    for (int j = 0; j < 4; ++j) v[j] = f2bf(src[j]);
    *reinterpret_cast<u16x4*>(reinterpret_cast<char*>(aT) + swz(row, c0 * 2, 512)) = v;
  }
  __syncthreads();
  const int nrep = (wv < 3) ? 2 : 1;
  for (int rep = 0; rep < nrep; ++rep) {
    int nt = wv + rep * 16;     // 0..18
    f32x4 acc = z4;
#pragma unroll
    for (int half = 0; half < 2; ++half) {
      bf16x8 b4[4];
#pragma unroll
      for (int i = 0; i < 4; ++i)
        b4[i] = *reinterpret_cast<const bf16x8*>(pkp + ((size_t)(nt * 8 + half * 4 + i) * 64 + lane) * 8);
#pragma unroll
      for (int i = 0; i < 4; ++i) {
        int kc = half * 4 + i;
        bf16x8 a = *reinterpret_cast<const bf16x8*>(
            reinterpret_cast<const char*>(aT) + swz(l15, kc * 64 + lg * 16, 512));
        acc = __builtin_amdgcn_mfma_f32_16x16x32_bf16(a, b4[i], acc, 0, 0, 0);
      }
    }
    int col = nt * 16 + l15;
    float bias = (col < 6) ? ref_b[col]
               : (col < 198) ? off_b[col - 6]
               : (col < 294) ? aw_b[col - 198] : 0.f;
#pragma unroll
    for (int r = 0; r < 4; ++r) {
      int m = lg * 4 + r;
      P[(r0 + m) * 304 + col] = acc[r] + bias;
    }
  }
}

// ---------------------------------------------------------------------------
// K2 v3: 2048 blocks — each (b,q) split across 2 blocks of 6 compile-time
// (l,p) points each (32 waves/CU vs 16). Partial agg -> partial GEMV ->
// atomicAdd into zeroed ctx (exactly 2 commutative fp32 adds/elem:
// deterministic). Gather math unchanged.
// ---------------------------------------------------------------------------
__global__ __launch_bounds__(256) void k2_fused(
    const float* __restrict__ P, const float* __restrict__ vis,
    const unsigned char* __restrict__ mask,
    const float* __restrict__ val_w, const float* __restrict__ val_b,
    float* __restrict__ ctx) {
  __shared__ float p_s[304];
  __shared__ float ref_s[6];
  __shared__ float aw_s[96];
  __shared__ float agg_s[8][260];
  __shared__ float csum_s[8];
  const int tid = threadIdx.x;
  const int bid = blockIdx.x;       // 0..2047
  const int bq = bid >> 1;          // b*64 + q
  const int hf = bid & 1;
  const int b = bq >> 6;
  p_s[tid] = P[(size_t)bq * 304 + tid];
  if (tid < 48) p_s[256 + tid] = P[(size_t)bq * 304 + 256 + tid];
  __syncthreads();
  if (tid < 6) ref_s[tid] = 1.f / (1.f + expf(-p_s[tid]));
  if (tid >= 8 && tid < 16) {
    int hh = tid - 8;
    float mx = -3.4e38f;
    for (int j = 0; j < 12; ++j) mx = fmaxf(mx, p_s[198 + hh * 12 + j]);
    float e[12]; float s = 0.f;
    for (int j = 0; j < 12; ++j) { e[j] = expf(p_s[198 + hh * 12 + j] - mx); s += e[j]; }
    float inv = 1.f / s;
    for (int j = 0; j < 12; ++j) aw_s[hh * 12 + j] = e[j] * inv;
  }
  __syncthreads();

  const int h = tid >> 5, d = tid & 31;
  float agg[8] = {0.f, 0.f, 0.f, 0.f, 0.f, 0.f, 0.f, 0.f};
  float csum = 0.f;
  const unsigned char* maskb = mask + (size_t)b * S_TOT;
  const float* visb = vis + (size_t)b * S_TOT * 256 + d * 8;

  auto do_point = [&](int l, int p, int Wl, int st) {
    const float Wf = (float)Wl;
    const int ip = (h * 3 + l) * 4 + p;
    const float rx = ref_s[l * 2 + 0], ry = ref_s[l * 2 + 1];
    const float ox = p_s[6 + ip * 2 + 0], oy = p_s[6 + ip * 2 + 1];
    const float aww = aw_s[ip];
    const float x = (rx + ox / Wf) * Wf - 0.5f;
    const float y = (ry + oy / Wf) * Wf - 0.5f;   // Hl == Wl (square levels)
    const float x0f = floorf(x), y0f = floorf(y);
    const float fx = x - x0f, fy = y - y0f;
    const int ix0 = (int)x0f, iy0 = (int)y0f;
    const bool xv0 = (unsigned)ix0 < (unsigned)Wl;
    const bool xv1 = (unsigned)(ix0 + 1) < (unsigned)Wl;
    const bool yv0 = (unsigned)iy0 < (unsigned)Wl;
    const bool yv1 = (unsigned)(iy0 + 1) < (unsigned)Wl;
    const int cx0 = min(max(ix0, 0), Wl - 1), cx1 = min(max(ix0 + 1, 0), Wl - 1);
    const int cy0 = min(max(iy0, 0), Wl - 1), cy1 = min(max(iy0 + 1, 0), Wl - 1);
    const int s00 = st + cy0 * Wl + cx0, s10 = st + cy0 * Wl + cx1;
    const int s01 = st + cy1 * Wl + cx0, s11 = st + cy1 * Wl + cx1;
    float w00 = (yv0 && xv0 && !maskb[s00]) ? aww * (1.f - fx) * (1.f - fy) : 0.f;
    float w10 = (yv0 && xv1 && !maskb[s10]) ? aww * fx * (1.f - fy) : 0.f;
    float w01 = (yv1 && xv0 && !maskb[s01]) ? aww * (1.f - fx) * fy : 0.f;
    float w11 = (yv1 && xv1 && !maskb[s11]) ? aww * fx * fy : 0.f;
    csum += w00 + w10 + w01 + w11;
    const float* p00 = visb + (size_t)s00 * 256;
    const float* p10 = visb + (size_t)s10 * 256;
    const float* p01 = visb + (size_t)s01 * 256;
    const float* p11 = visb + (size_t)s11 * 256;
    float4 a0 = *reinterpret_cast<const float4*>(p00);
    float4 a1 = *reinterpret_cast<const float4*>(p00 + 4);
    float4 b0 = *reinterpret_cast<const float4*>(p10);
    float4 b1 = *reinterpret_cast<const float4*>(p10 + 4);
    float4 c0 = *reinterpret_cast<const float4*>(p01);
    float4 c1 = *reinterpret_cast<const float4*>(p01 + 4);
    float4 e0 = *reinterpret_cast<const float4*>(p11);
    float4 e1 = *reinterpret_cast<const float4*>(p11 + 4);
    agg[0] += w00 * a0.x + w10 * b0.x + w01 * c0.x + w11 * e0.x;
    agg[1] += w00 * a0.y + w10 * b0.y + w01 * c0.y + w11 * e0.y;
    agg[2] += w00 * a0.z + w10 * b0.z + w01 * c0.z + w11 * e0.z;
    agg[3] += w00 * a0.w + w10 * b0.w + w01 * c0.w + w11 * e0.w;
    agg[4] += w00 * a1.x + w10 * b1.x + w01 * c1.x + w11 * e1.x;
    agg[5] += w00 * a1.y + w10 * b1.y + w01 * c1.y + w11 * e1.y;
    agg[6] += w00 * a1.z + w10 * b1.z + w01 * c1.z + w11 * e1.z;
    agg[7] += w00 * a1.w + w10 * b1.w + w01 * c1.w + w11 * e1.w;
  };

  if (hf == 0) {
    do_point(0, 0, 96, 0);
    do_point(0, 1, 96, 0);
    do_point(0, 2, 96, 0);
    do_point(0, 3, 96, 0);
    do_point(1, 0, 48, 9216);
    do_point(1, 1, 48, 9216);
  } else {
    do_point(1, 2, 48, 9216);
    do_point(1, 3, 48, 9216);
    do_point(2, 0, 24, 11520);
    do_point(2, 1, 24, 11520);
    do_point(2, 2, 24, 11520);
    do_point(2, 3, 24, 11520);
  }
#pragma unroll
  for (int j = 0; j < 8; ++j) agg_s[h][d * 8 + j] = agg[j];
  if (d == 0) csum_s[h] = csum;
  __syncthreads();

  float a = csum_s[h] * val_b[tid];
  for (int k = 0; k < 256; k += 4) {
    a += agg_s[h][k + 0] * val_w[(size_t)(k + 0) * 256 + tid];
    a += agg_s[h][k + 1] * val_w[(size_t)(k + 1) * 256 + tid];
    a += agg_s[h][k + 2] * val_w[(size_t)(k + 2) * 256 + tid];
    a += agg_s[h][k + 3] * val_w[(size_t)(k + 3) * 256 + tid];
  }
  atomicAdd(&ctx[(size_t)bq * 256 + tid], a);
}

// ---------------------------------------------------------------------------
// K3 v4: MFMA tail (r12-proven, byte-identical). 16 waves/block, 64 blocks.
// ---------------------------------------------------------------------------
__global__ __launch_bounds__(1024) void k3_mfma(
    const float* __restrict__ ctx, const float* __restrict__ text,
    const u16* __restrict__ pk,
    const float* __restrict__ proj_b, const float* __restrict__ out_b,
    const float* __restrict__ n1_g, const float* __restrict__ n1_b,
    const float* __restrict__ f1_b, const float* __restrict__ f2_b,
    const float* __restrict__ n2_g, const float* __restrict__ n2_b,
    float* __restrict__ outp) {
  __shared__ u16 aA[16 * 256];
  __shared__ u16 aY[16 * 256];
  __shared__ u16 aH[16 * 1024];
  __shared__ float fb[16 * 256];

  const int tid = threadIdx.x;
  const int lane = tid & 63, wv = tid >> 6;
  const int l15 = lane & 15, lg = lane >> 4;
  const size_t r0 = (size_t)blockIdx.x * 16;
  const f32x4 z4 = {0.f, 0.f, 0.f, 0.f};

  {
    int row = wv, c0 = lane * 4;
    const float* src = ctx + (r0 + row) * 256 + c0;
    u16x4 v;
#pragma unroll
    for (int j = 0; j < 4; ++j) v[j] = f2bf(src[j]);
    *reinterpret_cast<u16x4*>(reinterpret_cast<char*>(aA) + swz(row, c0 * 2, 512)) = v;
  }
  __syncthreads();

  {
    f32x4 acc = z4;
#pragma unroll
    for (int half = 0; half < 2; ++half) {
      bf16x8 b4[4];
#pragma unroll
      for (int i = 0; i < 4; ++i)
        b4[i] = *reinterpret_cast<const bf16x8*>(pk + ((wv * 8 + half * 4 + i) * 64 + lane) * 8);
#pragma unroll
      for (int i = 0; i < 4; ++i) {
        int kc = half * 4 + i;
        bf16x8 a = *reinterpret_cast<const bf16x8*>(
            reinterpret_cast<const char*>(aA) + swz(l15, kc * 64 + lg * 16, 512));
        acc = __builtin_amdgcn_mfma_f32_16x16x32_bf16(a, b4[i], acc, 0, 0, 0);
      }
    }
    int col = wv * 16 + l15;
    float bias = proj_b[col];
#pragma unroll
    for (int r = 0; r < 4; ++r) {
      int m = lg * 4 + r;
      *reinterpret_cast<u16*>(reinterpret_cast<char*>(aY) + swz(m, col * 2, 512)) =
          f2bf(acc[r] + bias);
    }
  }
  __syncthreads();

  {
    const u16* pko = pk + 65536;
    f32x4 acc = z4;
#pragma unroll
    for (int half = 0; half < 2; ++half) {
      bf16x8 b4[4];
#pragma unroll
      for (int i = 0; i < 4; ++i)
        b4[i] = *reinterpret_cast<const bf16x8*>(pko + ((wv * 8 + half * 4 + i) * 64 + lane) * 8);
#pragma unroll
      for (int i = 0; i < 4; ++i) {
        int kc = half * 4 + i;
        bf16x8 a = *reinterpret_cast<const bf16x8*>(
            reinterpret_cast<const char*>(aY) + swz(l15, kc * 64 + lg * 16, 512));
        acc = __builtin_amdgcn_mfma_f32_16x16x32_bf16(a, b4[i], acc, 0, 0, 0);
      }
    }
    int col = wv * 16 + l15;
    float bias = out_b[col];
#pragma unroll
    for (int r = 0; r < 4; ++r) {
      int m = lg * 4 + r;
      fb[m * 256 + col] = acc[r] + bias + text[(r0 + m) * 256 + col];
    }
  }
  __syncthreads();

  {
    int row = wv;
    float s = 0.f;
#pragma unroll
    for (int j = 0; j < 4; ++j) s += fb[row * 256 + lane + j * 64];
#pragma unroll
    for (int o = 1; o < 64; o <<= 1) s += __shfl_xor(s, o, 64);
    float mu = s * 0.00390625f;
    float vs = 0.f;
#pragma unroll
    for (int j = 0; j < 4; ++j) {
      float dd = fb[row * 256 + lane + j * 64] - mu; vs += dd * dd;
    }
#pragma unroll
    for (int o = 1; o < 64; o <<= 1) vs += __shfl_xor(vs, o, 64);
    float rs = rsqrtf(vs * 0.00390625f + 1e-5f);
#pragma unroll
    for (int j = 0; j < 4; ++j) {
      int col = lane + j * 64;
      float v = (fb[row * 256 + col] - mu) * rs * n1_g[col] + n1_b[col];
      fb[row * 256 + col] = v;
      *reinterpret_cast<u16*>(reinterpret_cast<char*>(aA) + swz(row, col * 2, 512)) = f2bf(v);
    }
  }
  __syncthreads();

  {
    const u16* pkf1 = pk + 131072;
#pragma unroll
    for (int nt = 0; nt < 4; ++nt) {
      int ntg = wv * 4 + nt;
      f32x4 acc = z4;
#pragma unroll
      for (int half = 0; half < 2; ++half) {
        bf16x8 b4[4];
#pragma unroll
        for (int i = 0; i < 4; ++i)
          b4[i] = *reinterpret_cast<const bf16x8*>(pkf1 + ((ntg * 8 + half * 4 + i) * 64 + lane) * 8);
#pragma unroll
        for (int i = 0; i < 4; ++i) {
          int kc = half * 4 + i;
          bf16x8 a = *reinterpret_cast<const bf16x8*>(
              reinterpret_cast<const char*>(aA) + swz(l15, kc * 64 + lg * 16, 512));
          acc = __builtin_amdgcn_mfma_f32_16x16x32_bf16(a, b4[i], acc, 0, 0, 0);
        }
      }
      int col = ntg * 16 + l15;
      float bias = f1_b[col];
#pragma unroll
      for (int r = 0; r < 4; ++r) {
        int m = lg * 4 + r;
        *reinterpret_cast<u16*>(reinterpret_cast<char*>(aH) + swz(m, col * 2, 2048)) =
            f2bf(fmaxf(acc[r] + bias, 0.f));
      }
    }
  }
  __syncthreads();

  {
    const u16* pkf2 = pk + 393216;
    f32x4 acc = z4;
#pragma unroll
    for (int c = 0; c < 8; ++c) {
      bf16x8 b4[4];
#pragma unroll
      for (int i = 0; i < 4; ++i)
        b4[i] = *reinterpret_cast<const bf16x8*>(pkf2 + ((wv * 32 + c * 4 + i) * 64 + lane) * 8);
#pragma unroll
      for (int i = 0; i < 4; ++i) {
        int kc = c * 4 + i;
        bf16x8 a = *reinterpret_cast<const bf16x8*>(
            reinterpret_cast<const char*>(aH) + swz(l15, kc * 64 + lg * 16, 2048));
        acc = __builtin_amdgcn_mfma_f32_16x16x32_bf16(a, b4[i], acc, 0, 0, 0);
      }
    }
    int col = wv * 16 + l15;
    float bias = f2_b[col];
#pragma unroll
    for (int r = 0; r < 4; ++r) {
      int m = lg * 4 + r;
      fb[m * 256 + col] = acc[r] + bias + fb[m * 256 + col];
    }
  }
  __syncthreads();

  {
    int row = wv;
    float s = 0.f;
#pragma unroll
    for (int j = 0; j < 4; ++j) s += fb[row * 256 + lane + j * 64];
#pragma unroll
    for (int o = 1; o < 64; o <<= 1) s += __shfl_xor(s, o, 64);
    float mu = s * 0.00390625f;
    float vs = 0.f;
#pragma unroll
    for (int j = 0; j < 4; ++j) {
      float dd = fb[row * 256 + lane + j * 64] - mu; vs += dd * dd;
    }
#pragma unroll
    for (int o = 1; o < 64; o <<= 1) vs += __shfl_xor(vs, o, 64);
    float rs = rsqrtf(vs * 0.00390625f + 1e-5f);
#pragma unroll
    for (int j = 0; j < 4; ++j) {
      int col = lane + j * 64;
      outp[(r0 + row) * 256 + col] = (fb[row * 256 + col] - mu) * rs * n2_g[col] + n2_b[col];
    }
  }
}

// ---------------------------------------------------------------------------
extern "C" void kernel_launch(void* const* d_in, const int* in_sizes, int n_in,
                              void* d_out, int out_size, void* d_ws, size_t ws_size,
                              hipStream_t stream) {
  const float* text  = (const float*)d_in[0];
  const float* vis   = (const float*)d_in[1];
  const unsigned char* mask = (const unsigned char*)d_in[4];
  const float* ref_w = (const float*)d_in[5];
  const float* ref_b = (const float*)d_in[6];
  const float* off_w = (const float*)d_in[7];
  const float* off_b = (const float*)d_in[8];
  const float* aw_w  = (const float*)d_in[9];
  const float* aw_b  = (const float*)d_in[10];
  const float* val_w = (const float*)d_in[11];
  const float* val_b = (const float*)d_in[12];
  const float* proj_w = (const float*)d_in[13];
  const float* proj_b = (const float*)d_in[14];
  const float* out_w = (const float*)d_in[15];
  const float* out_b = (const float*)d_in[16];
  const float* n1_g  = (const float*)d_in[17];
  const float* n1_b  = (const float*)d_in[18];
  const float* f1_w  = (const float*)d_in[19];
  const float* f1_b  = (const float*)d_in[20];
  const float* f2_w  = (const float*)d_in[21];
  const float* f2_b  = (const float*)d_in[22];
  const float* n2_g  = (const float*)d_in[23];
  const float* n2_b  = (const float*)d_in[24];
  float* outp = (float*)d_out;

  char* ws = (char*)d_ws;
  float* ctx = (float*)ws;                            // 1.0 MB
  u16* pk    = (u16*)(ws + (size_t)1024 * 1024);      // 1.4 MB packed weights
  u16* pkp   = pk + (size_t)81920 * 8;                // proj-weight fragments
  float* P   = (float*)(ws + (size_t)2560 * 1024);    // 1.22 MB projections

  k_pack<<<78, 256, 0, stream>>>(proj_w, out_w, f1_w, f2_w, ref_w, off_w, aw_w, pk);
  k_proj<<<64, 1024, 0, stream>>>(text, pkp, ref_b, off_b, aw_b, P, ctx);
  k2_fused<<<2048, 256, 0, stream>>>(P, vis, mask, val_w, val_b, ctx);
  k3_mfma<<<64, 1024, 0, stream>>>(ctx, text, pk, proj_b, out_b,
                                   n1_g, n1_b, f1_b, f2_b, n2_g, n2_b, outp);
}

// Round 17
// 77.426 us; speedup vs baseline: 10.9969x; 1.0964x over previous
//
#include <hip/hip_runtime.h>

#define S_TOT 12096
typedef unsigned short u16;
typedef __attribute__((ext_vector_type(4))) unsigned short u16x4;
typedef __attribute__((ext_vector_type(8))) unsigned short u16x8;
typedef __attribute__((ext_vector_type(8))) short bf16x8;
typedef __attribute__((ext_vector_type(4))) float f32x4;

__device__ __forceinline__ u16 f2bf(float f) {
  union { float f; unsigned u; } v; v.f = f;
  unsigned r = v.u + 0x7FFFu + ((v.u >> 16) & 1u);  // round-nearest-even
  return (u16)(r >> 16);
}

// ---------------------------------------------------------------------------
// k_pack: 0..39 big-weight pack (r13-proven) | 40..43 val_w pack (same LDS
// path, base8=91648) | 44..81 proj-weight pack.
// ---------------------------------------------------------------------------
__global__ __launch_bounds__(256) void k_pack(
    const float* __restrict__ pw, const float* __restrict__ ow,
    const float* __restrict__ f1w, const float* __restrict__ f2w,
    const float* __restrict__ vw,
    const float* __restrict__ rfw, const float* __restrict__ ofw,
    const float* __restrict__ awW,
    u16* __restrict__ dst) {
  const int t = threadIdx.x;
  const int bid = blockIdx.x;   // 0..81
  if (bid >= 44) {              // ---- projection-weight pack ----
    int t2 = (bid - 44) * 256 + t;        // 0..9727
    int ln = t2 & 63;
    int kc = (t2 >> 6) & 7;
    int nt = t2 >> 9;                     // 0..18
    int col = nt * 16 + (ln & 15);
    int k0 = kc * 32 + (ln >> 4) * 8;
    u16x8 v;
#pragma unroll
    for (int e = 0; e < 8; ++e) {
      int k = k0 + e;
      float val;
      if (col < 6)        val = rfw[k * 6 + col];
      else if (col < 198) val = ofw[k * 192 + (col - 6)];
      else if (col < 294) val = awW[k * 96 + (col - 198)];
      else                val = 0.f;
      v[e] = f2bf(val);
    }
    *reinterpret_cast<u16x8*>(dst + ((size_t)81920 + (size_t)(nt * 8 + kc) * 64 + ln) * 8) = v;
    return;
  }
  __shared__ float ls[16384];   // 64 KB tile
  const float* src; int nc, KC, base8, r0;
  if (bid < 4)       { src = pw;  nc = 256;  KC = 8;  base8 = 0;     r0 = bid * 64; }
  else if (bid < 8)  { src = ow;  nc = 256;  KC = 8;  base8 = 8192;  r0 = (bid - 4) * 64; }
  else if (bid < 24) { src = f2w; nc = 256;  KC = 32; base8 = 49152; r0 = (bid - 8) * 64; }
  else if (bid < 40) { src = f1w; nc = 1024; KC = 8;  base8 = 16384; r0 = (bid - 24) * 16; }
  else               { src = vw;  nc = 256;  KC = 8;  base8 = 91648; r0 = (bid - 40) * 64; }
  const float* sp = src + (size_t)r0 * nc;
#pragma unroll
  for (int i = 0; i < 16; ++i) {
    int fi = (i * 256 + t) * 4;
    *reinterpret_cast<float4*>(&ls[fi]) = *reinterpret_cast<const float4*>(sp + fi);
  }
  __syncthreads();
  if (nc == 256) {
    int kc0 = r0 >> 5;
#pragma unroll
    for (int f = 0; f < 8; ++f) {
      int fid = f * 256 + t;
      int kcl = fid >> 10, nt = (fid >> 6) & 15, ln = fid & 63;
      int n = nt * 16 + (ln & 15);
      int rb = kcl * 32 + (ln >> 4) * 8;
      u16x8 v;
#pragma unroll
      for (int e = 0; e < 8; ++e) v[e] = f2bf(ls[(rb + e) * 256 + n]);
      *reinterpret_cast<u16x8*>(
          dst + ((size_t)base8 + (size_t)(nt * KC + kc0 + kcl) * 64 + ln) * 8) = v;
    }
  } else {
    int kc = r0 >> 5, half = (r0 & 16) ? 32 : 0;
#pragma unroll
    for (int f = 0; f < 8; ++f) {
      int fid = f * 256 + t;
      int nt = fid >> 5, lnh = fid & 31;
      int ln = lnh + half;
      int n = nt * 16 + (ln & 15);
      int rb = ((ln >> 4) & 1) * 8;
      u16x8 v;
#pragma unroll
      for (int e = 0; e < 8; ++e) v[e] = f2bf(ls[(rb + e) * 1024 + n]);
      *reinterpret_cast<u16x8*>(
          dst + ((size_t)base8 + (size_t)(nt * 8 + kc) * 64 + ln) * 8) = v;
    }
  }
}

// ---------------------------------------------------------------------------
__device__ __forceinline__ int swz(int row, int bytecol, int rowbytes) {
  return (row * rowbytes + bytecol) ^ ((row & 7) << 4);
}

// ---------------------------------------------------------------------------
// k_proj: P[1024 x 304] = text @ [ref_w|off_w|aw_w|0] + bias (r15-proven).
// ---------------------------------------------------------------------------
__global__ __launch_bounds__(1024) void k_proj(
    const float* __restrict__ text, const u16* __restrict__ pkp,
    const float* __restrict__ ref_b, const float* __restrict__ off_b,
    const float* __restrict__ aw_b, float* __restrict__ P) {
  __shared__ u16 aT[16 * 256];
  const int tid = threadIdx.x;
  const int lane = tid & 63, wv = tid >> 6;
  const int l15 = lane & 15, lg = lane >> 4;
  const size_t r0 = (size_t)blockIdx.x * 16;
  const f32x4 z4 = {0.f, 0.f, 0.f, 0.f};
  {
    int row = wv, c0 = lane * 4;
    const float* src = text + (r0 + row) * 256 + c0;
    u16x4 v;
#pragma unroll
    for (int j = 0; j < 4; ++j) v[j] = f2bf(src[j]);
    *reinterpret_cast<u16x4*>(reinterpret_cast<char*>(aT) + swz(row, c0 * 2, 512)) = v;
  }
  __syncthreads();
  const int nrep = (wv < 3) ? 2 : 1;
  for (int rep = 0; rep < nrep; ++rep) {
    int nt = wv + rep * 16;     // 0..18
    f32x4 acc = z4;
#pragma unroll
    for (int half = 0; half < 2; ++half) {
      bf16x8 b4[4];
#pragma unroll
      for (int i = 0; i < 4; ++i)
        b4[i] = *reinterpret_cast<const bf16x8*>(pkp + ((size_t)(nt * 8 + half * 4 + i) * 64 + lane) * 8);
#pragma unroll
      for (int i = 0; i < 4; ++i) {
        int kc = half * 4 + i;
        bf16x8 a = *reinterpret_cast<const bf16x8*>(
            reinterpret_cast<const char*>(aT) + swz(l15, kc * 64 + lg * 16, 512));
        acc = __builtin_amdgcn_mfma_f32_16x16x32_bf16(a, b4[i], acc, 0, 0, 0);
      }
    }
    int col = nt * 16 + l15;
    float bias = (col < 6) ? ref_b[col]
               : (col < 198) ? off_b[col - 6]
               : (col < 294) ? aw_b[col - 198] : 0.f;
#pragma unroll
    for (int r = 0; r < 4; ++r) {
      int m = lg * 4 + r;
      P[(r0 + m) * 304 + col] = acc[r] + bias;
    }
  }
}

// ---------------------------------------------------------------------------
// K2 v4: gather only. 2048 blocks, XCD-remapped (batch-per-XCD locality).
// Writes raw partial aggregates to AGG[2][1024][8][256] + CSUM (no atomics,
// no GEMV, no zero-init). Gather math unchanged (r16-proven).
// ---------------------------------------------------------------------------
__global__ __launch_bounds__(256) void k2_fused(
    const float* __restrict__ P, const float* __restrict__ vis,
    const unsigned char* __restrict__ mask,
    float* __restrict__ AGG, float* __restrict__ CSUM) {
  __shared__ float p_s[304];
  __shared__ float ref_s[6];
  __shared__ float aw_s[96];
  const int tid = threadIdx.x;
  // XCD-aware remap: all 128 blocks of a batch on one XCD (bid%8 heuristic).
  const int xcd = blockIdx.x & 7;
  const int idx = blockIdx.x >> 3;        // 0..255
  const int b = xcd * 2 + (idx >> 7);
  const int rem = idx & 127;
  const int bq = b * 64 + (rem >> 1);
  const int hf = rem & 1;
  p_s[tid] = P[(size_t)bq * 304 + tid];
  if (tid < 48) p_s[256 + tid] = P[(size_t)bq * 304 + 256 + tid];
  __syncthreads();
  if (tid < 6) ref_s[tid] = 1.f / (1.f + expf(-p_s[tid]));
  if (tid >= 8 && tid < 16) {
    int hh = tid - 8;
    float mx = -3.4e38f;
    for (int j = 0; j < 12; ++j) mx = fmaxf(mx, p_s[198 + hh * 12 + j]);
    float e[12]; float s = 0.f;
    for (int j = 0; j < 12; ++j) { e[j] = expf(p_s[198 + hh * 12 + j] - mx); s += e[j]; }
    float inv = 1.f / s;
    for (int j = 0; j < 12; ++j) aw_s[hh * 12 + j] = e[j] * inv;
  }
  __syncthreads();

  const int h = tid >> 5, d = tid & 31;
  float agg[8] = {0.f, 0.f, 0.f, 0.f, 0.f, 0.f, 0.f, 0.f};
  float csum = 0.f;
  const unsigned char* maskb = mask + (size_t)b * S_TOT;
  const float* visb = vis + (size_t)b * S_TOT * 256 + d * 8;

  auto do_point = [&](int l, int p, int Wl, int st) {
    const float Wf = (float)Wl;
    const int ip = (h * 3 + l) * 4 + p;
    const float rx = ref_s[l * 2 + 0], ry = ref_s[l * 2 + 1];
    const float ox = p_s[6 + ip * 2 + 0], oy = p_s[6 + ip * 2 + 1];
    const float aww = aw_s[ip];
    const float x = (rx + ox / Wf) * Wf - 0.5f;
    const float y = (ry + oy / Wf) * Wf - 0.5f;   // Hl == Wl (square levels)
    const float x0f = floorf(x), y0f = floorf(y);
    const float fx = x - x0f, fy = y - y0f;
    const int ix0 = (int)x0f, iy0 = (int)y0f;
    const bool xv0 = (unsigned)ix0 < (unsigned)Wl;
    const bool xv1 = (unsigned)(ix0 + 1) < (unsigned)Wl;
    const bool yv0 = (unsigned)iy0 < (unsigned)Wl;
    const bool yv1 = (unsigned)(iy0 + 1) < (unsigned)Wl;
    const int cx0 = min(max(ix0, 0), Wl - 1), cx1 = min(max(ix0 + 1, 0), Wl - 1);
    const int cy0 = min(max(iy0, 0), Wl - 1), cy1 = min(max(iy0 + 1, 0), Wl - 1);
    const int s00 = st + cy0 * Wl + cx0, s10 = st + cy0 * Wl + cx1;
    const int s01 = st + cy1 * Wl + cx0, s11 = st + cy1 * Wl + cx1;
    float w00 = (yv0 && xv0 && !maskb[s00]) ? aww * (1.f - fx) * (1.f - fy) : 0.f;
    float w10 = (yv0 && xv1 && !maskb[s10]) ? aww * fx * (1.f - fy) : 0.f;
    float w01 = (yv1 && xv0 && !maskb[s01]) ? aww * (1.f - fx) * fy : 0.f;
    float w11 = (yv1 && xv1 && !maskb[s11]) ? aww * fx * fy : 0.f;
    csum += w00 + w10 + w01 + w11;
    const float* p00 = visb + (size_t)s00 * 256;
    const float* p10 = visb + (size_t)s10 * 256;
    const float* p01 = visb + (size_t)s01 * 256;
    const float* p11 = visb + (size_t)s11 * 256;
    float4 a0 = *reinterpret_cast<const float4*>(p00);
    float4 a1 = *reinterpret_cast<const float4*>(p00 + 4);
    float4 b0 = *reinterpret_cast<const float4*>(p10);
    float4 b1 = *reinterpret_cast<const float4*>(p10 + 4);
    float4 c0 = *reinterpret_cast<const float4*>(p01);
    float4 c1 = *reinterpret_cast<const float4*>(p01 + 4);
    float4 e0 = *reinterpret_cast<const float4*>(p11);
    float4 e1 = *reinterpret_cast<const float4*>(p11 + 4);
    agg[0] += w00 * a0.x + w10 * b0.x + w01 * c0.x + w11 * e0.x;
    agg[1] += w00 * a0.y + w10 * b0.y + w01 * c0.y + w11 * e0.y;
    agg[2] += w00 * a0.z + w10 * b0.z + w01 * c0.z + w11 * e0.z;
    agg[3] += w00 * a0.w + w10 * b0.w + w01 * c0.w + w11 * e0.w;
    agg[4] += w00 * a1.x + w10 * b1.x + w01 * c1.x + w11 * e1.x;
    agg[5] += w00 * a1.y + w10 * b1.y + w01 * c1.y + w11 * e1.y;
    agg[6] += w00 * a1.z + w10 * b1.z + w01 * c1.z + w11 * e1.z;
    agg[7] += w00 * a1.w + w10 * b1.w + w01 * c1.w + w11 * e1.w;
  };

  if (hf == 0) {
    do_point(0, 0, 96, 0);
    do_point(0, 1, 96, 0);
    do_point(0, 2, 96, 0);
    do_point(0, 3, 96, 0);
    do_point(1, 0, 48, 9216);
    do_point(1, 1, 48, 9216);
  } else {
    do_point(1, 2, 48, 9216);
    do_point(1, 3, 48, 9216);
    do_point(2, 0, 24, 11520);
    do_point(2, 1, 24, 11520);
    do_point(2, 2, 24, 11520);
    do_point(2, 3, 24, 11520);
  }
  float* ap = AGG + (((size_t)hf * 1024 + bq) * 8 + h) * 256 + d * 8;
  float4 v0 = {agg[0], agg[1], agg[2], agg[3]};
  float4 v1 = {agg[4], agg[5], agg[6], agg[7]};
  *reinterpret_cast<float4*>(ap) = v0;
  *reinterpret_cast<float4*>(ap + 4) = v1;
  if (d == 0) CSUM[((size_t)hf * 1024 + bq) * 8 + h] = csum;
}

// ---------------------------------------------------------------------------
// k_ctx: ctx[1024 x 256] = per-head GEMM of (AGG0+AGG1) vs packed val_w,
// + (csum0+csum1)*val_b. 64 blocks x 16 waves; wave wv -> head wv>>1.
// ---------------------------------------------------------------------------
__global__ __launch_bounds__(1024) void k_ctx(
    const float* __restrict__ AGG, const float* __restrict__ CSUM,
    const u16* __restrict__ pkv, const float* __restrict__ val_b,
    float* __restrict__ ctx) {
  __shared__ u16 aG[16 * 2048];   // 64 KB: summed AGG rows, bf16, swizzled
  __shared__ float cs_s[16][8];
  const int tid = threadIdx.x;
  const int lane = tid & 63, wv = tid >> 6;
  const int l15 = lane & 15, lg = lane >> 4;
  const size_t r0 = (size_t)blockIdx.x * 16;
  const f32x4 z4 = {0.f, 0.f, 0.f, 0.f};
  {
    int row = tid >> 6, c0 = (tid & 63) * 32;
    const float* s0 = AGG + ((size_t)(r0 + row)) * 2048 + c0;
    const float* s1 = s0 + (size_t)1024 * 2048;
#pragma unroll
    for (int j = 0; j < 4; ++j) {
      float4 x0 = *reinterpret_cast<const float4*>(s0 + j * 8);
      float4 x1 = *reinterpret_cast<const float4*>(s0 + j * 8 + 4);
      float4 y0 = *reinterpret_cast<const float4*>(s1 + j * 8);
      float4 y1 = *reinterpret_cast<const float4*>(s1 + j * 8 + 4);
      u16x8 v;
      v[0] = f2bf(x0.x + y0.x); v[1] = f2bf(x0.y + y0.y);
      v[2] = f2bf(x0.z + y0.z); v[3] = f2bf(x0.w + y0.w);
      v[4] = f2bf(x1.x + y1.x); v[5] = f2bf(x1.y + y1.y);
      v[6] = f2bf(x1.z + y1.z); v[7] = f2bf(x1.w + y1.w);
      *reinterpret_cast<u16x8*>(reinterpret_cast<char*>(aG) +
                                swz(row, (c0 + j * 8) * 2, 4096)) = v;
    }
    if (tid < 128) {
      int rr = tid >> 3, hh = tid & 7;
      cs_s[rr][hh] = CSUM[(r0 + rr) * 8 + hh] + CSUM[(1024 + r0 + rr) * 8 + hh];
    }
  }
  __syncthreads();
  {
    const int h = wv >> 1;
    bf16x8 b8[8];
#pragma unroll
    for (int kc = 0; kc < 8; ++kc)
      b8[kc] = *reinterpret_cast<const bf16x8*>(pkv + ((size_t)(wv * 8 + kc) * 64 + lane) * 8);
    f32x4 acc = z4;
#pragma unroll
    for (int kc = 0; kc < 8; ++kc) {
      bf16x8 a = *reinterpret_cast<const bf16x8*>(
          reinterpret_cast<const char*>(aG) + swz(l15, h * 512 + kc * 64 + lg * 16, 4096));
      acc = __builtin_amdgcn_mfma_f32_16x16x32_bf16(a, b8[kc], acc, 0, 0, 0);
    }
    int col = wv * 16 + l15;
    float vb = val_b[col];
#pragma unroll
    for (int r = 0; r < 4; ++r) {
      int m = lg * 4 + r;
      ctx[(r0 + m) * 256 + col] = acc[r] + cs_s[m][h] * vb;
    }
  }
}

// ---------------------------------------------------------------------------
// K3 v4: MFMA tail (r12-proven, byte-identical). 16 waves/block, 64 blocks.
// ---------------------------------------------------------------------------
__global__ __launch_bounds__(1024) void k3_mfma(
    const float* __restrict__ ctx, const float* __restrict__ text,
    const u16* __restrict__ pk,
    const float* __restrict__ proj_b, const float* __restrict__ out_b,
    const float* __restrict__ n1_g, const float* __restrict__ n1_b,
    const float* __restrict__ f1_b, const float* __restrict__ f2_b,
    const float* __restrict__ n2_g, const float* __restrict__ n2_b,
    float* __restrict__ outp) {
  __shared__ u16 aA[16 * 256];
  __shared__ u16 aY[16 * 256];
  __shared__ u16 aH[16 * 1024];
  __shared__ float fb[16 * 256];

  const int tid = threadIdx.x;
  const int lane = tid & 63, wv = tid >> 6;
  const int l15 = lane & 15, lg = lane >> 4;
  const size_t r0 = (size_t)blockIdx.x * 16;
  const f32x4 z4 = {0.f, 0.f, 0.f, 0.f};

  {
    int row = wv, c0 = lane * 4;
    const float* src = ctx + (r0 + row) * 256 + c0;
    u16x4 v;
#pragma unroll
    for (int j = 0; j < 4; ++j) v[j] = f2bf(src[j]);
    *reinterpret_cast<u16x4*>(reinterpret_cast<char*>(aA) + swz(row, c0 * 2, 512)) = v;
  }
  __syncthreads();

  {
    f32x4 acc = z4;
#pragma unroll
    for (int half = 0; half < 2; ++half) {
      bf16x8 b4[4];
#pragma unroll
      for (int i = 0; i < 4; ++i)
        b4[i] = *reinterpret_cast<const bf16x8*>(pk + ((wv * 8 + half * 4 + i) * 64 + lane) * 8);
#pragma unroll
      for (int i = 0; i < 4; ++i) {
        int kc = half * 4 + i;
        bf16x8 a = *reinterpret_cast<const bf16x8*>(
            reinterpret_cast<const char*>(aA) + swz(l15, kc * 64 + lg * 16, 512));
        acc = __builtin_amdgcn_mfma_f32_16x16x32_bf16(a, b4[i], acc, 0, 0, 0);
      }
    }
    int col = wv * 16 + l15;
    float bias = proj_b[col];
#pragma unroll
    for (int r = 0; r < 4; ++r) {
      int m = lg * 4 + r;
      *reinterpret_cast<u16*>(reinterpret_cast<char*>(aY) + swz(m, col * 2, 512)) =
          f2bf(acc[r] + bias);
    }
  }
  __syncthreads();

  {
    const u16* pko = pk + 65536;
    f32x4 acc = z4;
#pragma unroll
    for (int half = 0; half < 2; ++half) {
      bf16x8 b4[4];
#pragma unroll
      for (int i = 0; i < 4; ++i)
        b4[i] = *reinterpret_cast<const bf16x8*>(pko + ((wv * 8 + half * 4 + i) * 64 + lane) * 8);
#pragma unroll
      for (int i = 0; i < 4; ++i) {
        int kc = half * 4 + i;
        bf16x8 a = *reinterpret_cast<const bf16x8*>(
            reinterpret_cast<const char*>(aY) + swz(l15, kc * 64 + lg * 16, 512));
        acc = __builtin_amdgcn_mfma_f32_16x16x32_bf16(a, b4[i], acc, 0, 0, 0);
      }
    }
    int col = wv * 16 + l15;
    float bias = out_b[col];
#pragma unroll
    for (int r = 0; r < 4; ++r) {
      int m = lg * 4 + r;
      fb[m * 256 + col] = acc[r] + bias + text[(r0 + m) * 256 + col];
    }
  }
  __syncthreads();

  {
    int row = wv;
    float s = 0.f;
#pragma unroll
    for (int j = 0; j < 4; ++j) s += fb[row * 256 + lane + j * 64];
#pragma unroll
    for (int o = 1; o < 64; o <<= 1) s += __shfl_xor(s, o, 64);
    float mu = s * 0.00390625f;
    float vs = 0.f;
#pragma unroll
    for (int j = 0; j < 4; ++j) {
      float dd = fb[row * 256 + lane + j * 64] - mu; vs += dd * dd;
    }
#pragma unroll
    for (int o = 1; o < 64; o <<= 1) vs += __shfl_xor(vs, o, 64);
    float rs = rsqrtf(vs * 0.00390625f + 1e-5f);
#pragma unroll
    for (int j = 0; j < 4; ++j) {
      int col = lane + j * 64;
      float v = (fb[row * 256 + col] - mu) * rs * n1_g[col] + n1_b[col];
      fb[row * 256 + col] = v;
      *reinterpret_cast<u16*>(reinterpret_cast<char*>(aA) + swz(row, col * 2, 512)) = f2bf(v);
    }
  }
  __syncthreads();

  {
    const u16* pkf1 = pk + 131072;
#pragma unroll
    for (int nt = 0; nt < 4; ++nt) {
      int ntg = wv * 4 + nt;
      f32x4 acc = z4;
#pragma unroll
      for (int half = 0; half < 2; ++half) {
        bf16x8 b4[4];
#pragma unroll
        for (int i = 0; i < 4; ++i)
          b4[i] = *reinterpret_cast<const bf16x8*>(pkf1 + ((ntg * 8 + half * 4 + i) * 64 + lane) * 8);
#pragma unroll
        for (int i = 0; i < 4; ++i) {
          int kc = half * 4 + i;
          bf16x8 a = *reinterpret_cast<const bf16x8*>(
              reinterpret_cast<const char*>(aA) + swz(l15, kc * 64 + lg * 16, 512));
          acc = __builtin_amdgcn_mfma_f32_16x16x32_bf16(a, b4[i], acc, 0, 0, 0);
        }
      }
      int col = ntg * 16 + l15;
      float bias = f1_b[col];
#pragma unroll
      for (int r = 0; r < 4; ++r) {
        int m = lg * 4 + r;
        *reinterpret_cast<u16*>(reinterpret_cast<char*>(aH) + swz(m, col * 2, 2048)) =
            f2bf(fmaxf(acc[r] + bias, 0.f));
      }
    }
  }
  __syncthreads();

  {
    const u16* pkf2 = pk + 393216;
    f32x4 acc = z4;
#pragma unroll
    for (int c = 0; c < 8; ++c) {
      bf16x8 b4[4];
#pragma unroll
      for (int i = 0; i < 4; ++i)
        b4[i] = *reinterpret_cast<const bf16x8*>(pkf2 + ((wv * 32 + c * 4 + i) * 64 + lane) * 8);
#pragma unroll
      for (int i = 0; i < 4; ++i) {
        int kc = c * 4 + i;
        bf16x8 a = *reinterpret_cast<const bf16x8*>(
            reinterpret_cast<const char*>(aH) + swz(l15, kc * 64 + lg * 16, 2048));
        acc = __builtin_amdgcn_mfma_f32_16x16x32_bf16(a, b4[i], acc, 0, 0, 0);
      }
    }
    int col = wv * 16 + l15;
    float bias = f2_b[col];
#pragma unroll
    for (int r = 0; r < 4; ++r) {
      int m = lg * 4 + r;
      fb[m * 256 + col] = acc[r] + bias + fb[m * 256 + col];
    }
  }
  __syncthreads();

  {
    int row = wv;
    float s = 0.f;
#pragma unroll
    for (int j = 0; j < 4; ++j) s += fb[row * 256 + lane + j * 64];
#pragma unroll
    for (int o = 1; o < 64; o <<= 1) s += __shfl_xor(s, o, 64);
    float mu = s * 0.00390625f;
    float vs = 0.f;
#pragma unroll
    for (int j = 0; j < 4; ++j) {
      float dd = fb[row * 256 + lane + j * 64] - mu; vs += dd * dd;
    }
#pragma unroll
    for (int o = 1; o < 64; o <<= 1) vs += __shfl_xor(vs, o, 64);
    float rs = rsqrtf(vs * 0.00390625f + 1e-5f);
#pragma unroll
    for (int j = 0; j < 4; ++j) {
      int col = lane + j * 64;
      outp[(r0 + row) * 256 + col] = (fb[row * 256 + col] - mu) * rs * n2_g[col] + n2_b[col];
    }
  }
}

// ---------------------------------------------------------------------------
extern "C" void kernel_launch(void* const* d_in, const int* in_sizes, int n_in,
                              void* d_out, int out_size, void* d_ws, size_t ws_size,
                              hipStream_t stream) {
  const float* text  = (const float*)d_in[0];
  const float* vis   = (const float*)d_in[1];
  const unsigned char* mask = (const unsigned char*)d_in[4];
  const float* ref_w = (const float*)d_in[5];
  const float* ref_b = (const float*)d_in[6];
  const float* off_w = (const float*)d_in[7];
  const float* off_b = (const float*)d_in[8];
  const float* aw_w  = (const float*)d_in[9];
  const float* aw_b  = (const float*)d_in[10];
  const float* val_w = (const float*)d_in[11];
  const float* val_b = (const float*)d_in[12];
  const float* proj_w = (const float*)d_in[13];
  const float* proj_b = (const float*)d_in[14];
  const float* out_w = (const float*)d_in[15];
  const float* out_b = (const float*)d_in[16];
  const float* n1_g  = (const float*)d_in[17];
  const float* n1_b  = (const float*)d_in[18];
  const float* f1_w  = (const float*)d_in[19];
  const float* f1_b  = (const float*)d_in[20];
  const float* f2_w  = (const float*)d_in[21];
  const float* f2_b  = (const float*)d_in[22];
  const float* n2_g  = (const float*)d_in[23];
  const float* n2_b  = (const float*)d_in[24];
  float* outp = (float*)d_out;

  char* ws = (char*)d_ws;
  float* ctx = (float*)ws;                              // [0, 1 MB)
  u16* pk    = (u16*)(ws + (size_t)1024 * 1024);        // [1, ~2.6 MB)
  u16* pkp   = pk + (size_t)81920 * 8;                  // proj fragments
  u16* pkv   = pk + (size_t)91648 * 8;                  // val_w fragments
  float* P   = (float*)(ws + (size_t)4 * 1024 * 1024);  // [4, 5.25 MB)
  float* AGG = (float*)(ws + (size_t)6 * 1024 * 1024);  // [6, 22 MB)
  float* CSUM = (float*)(ws + (size_t)23 * 1024 * 1024);// 64 KB

  k_pack<<<82, 256, 0, stream>>>(proj_w, out_w, f1_w, f2_w, val_w,
                                 ref_w, off_w, aw_w, pk);
  k_proj<<<64, 1024, 0, stream>>>(text, pkp, ref_b, off_b, aw_b, P);
  k2_fused<<<2048, 256, 0, stream>>>(P, vis, mask, AGG, CSUM);
  k_ctx<<<64, 1024, 0, stream>>>(AGG, CSUM, pkv, val_b, ctx);
  k3_mfma<<<64, 1024, 0, stream>>>(ctx, text, pk, proj_b, out_b,
                                   n1_g, n1_b, f1_b, f2_b, n2_g, n2_b, outp);
}

// Round 18
// 66.955 us; speedup vs baseline: 12.7168x; 1.1564x over previous
//
#include <hip/hip_runtime.h>

#define S_TOT 12096
typedef unsigned short u16;
typedef __attribute__((ext_vector_type(4))) unsigned short u16x4;
typedef __attribute__((ext_vector_type(8))) unsigned short u16x8;
typedef __attribute__((ext_vector_type(8))) short bf16x8;
typedef __attribute__((ext_vector_type(4))) float f32x4;

__device__ __forceinline__ u16 f2bf(float f) {
  union { float f; unsigned u; } v; v.f = f;
  unsigned r = v.u + 0x7FFFu + ((v.u >> 16) & 1u);  // round-nearest-even
  return (u16)(r >> 16);
}
__device__ __forceinline__ float bf2f(u16 h) {
  union { unsigned u; float f; } v; v.u = ((unsigned)h) << 16; return v.f;
}

// ---------------------------------------------------------------------------
// k_pack: 0..39 big weights | 40..43 val_w | 44..81 proj weights (r17-proven).
// ---------------------------------------------------------------------------
__global__ __launch_bounds__(256) void k_pack(
    const float* __restrict__ pw, const float* __restrict__ ow,
    const float* __restrict__ f1w, const float* __restrict__ f2w,
    const float* __restrict__ vw,
    const float* __restrict__ rfw, const float* __restrict__ ofw,
    const float* __restrict__ awW,
    u16* __restrict__ dst) {
  const int t = threadIdx.x;
  const int bid = blockIdx.x;   // 0..81
  if (bid >= 44) {              // ---- projection-weight pack ----
    int t2 = (bid - 44) * 256 + t;        // 0..9727
    int ln = t2 & 63;
    int kc = (t2 >> 6) & 7;
    int nt = t2 >> 9;                     // 0..18
    int col = nt * 16 + (ln & 15);
    int k0 = kc * 32 + (ln >> 4) * 8;
    u16x8 v;
#pragma unroll
    for (int e = 0; e < 8; ++e) {
      int k = k0 + e;
      float val;
      if (col < 6)        val = rfw[k * 6 + col];
      else if (col < 198) val = ofw[k * 192 + (col - 6)];
      else if (col < 294) val = awW[k * 96 + (col - 198)];
      else                val = 0.f;
      v[e] = f2bf(val);
    }
    *reinterpret_cast<u16x8*>(dst + ((size_t)81920 + (size_t)(nt * 8 + kc) * 64 + ln) * 8) = v;
    return;
  }
  __shared__ float ls[16384];   // 64 KB tile
  const float* src; int nc, KC, base8, r0;
  if (bid < 4)       { src = pw;  nc = 256;  KC = 8;  base8 = 0;     r0 = bid * 64; }
  else if (bid < 8)  { src = ow;  nc = 256;  KC = 8;  base8 = 8192;  r0 = (bid - 4) * 64; }
  else if (bid < 24) { src = f2w; nc = 256;  KC = 32; base8 = 49152; r0 = (bid - 8) * 64; }
  else if (bid < 40) { src = f1w; nc = 1024; KC = 8;  base8 = 16384; r0 = (bid - 24) * 16; }
  else               { src = vw;  nc = 256;  KC = 8;  base8 = 91648; r0 = (bid - 40) * 64; }
  const float* sp = src + (size_t)r0 * nc;
#pragma unroll
  for (int i = 0; i < 16; ++i) {
    int fi = (i * 256 + t) * 4;
    *reinterpret_cast<float4*>(&ls[fi]) = *reinterpret_cast<const float4*>(sp + fi);
  }
  __syncthreads();
  if (nc == 256) {
    int kc0 = r0 >> 5;
#pragma unroll
    for (int f = 0; f < 8; ++f) {
      int fid = f * 256 + t;
      int kcl = fid >> 10, nt = (fid >> 6) & 15, ln = fid & 63;
      int n = nt * 16 + (ln & 15);
      int rb = kcl * 32 + (ln >> 4) * 8;
      u16x8 v;
#pragma unroll
      for (int e = 0; e < 8; ++e) v[e] = f2bf(ls[(rb + e) * 256 + n]);
      *reinterpret_cast<u16x8*>(
          dst + ((size_t)base8 + (size_t)(nt * KC + kc0 + kcl) * 64 + ln) * 8) = v;
    }
  } else {
    int kc = r0 >> 5, half = (r0 & 16) ? 32 : 0;
#pragma unroll
    for (int f = 0; f < 8; ++f) {
      int fid = f * 256 + t;
      int nt = fid >> 5, lnh = fid & 31;
      int ln = lnh + half;
      int n = nt * 16 + (ln & 15);
      int rb = ((ln >> 4) & 1) * 8;
      u16x8 v;
#pragma unroll
      for (int e = 0; e < 8; ++e) v[e] = f2bf(ls[(rb + e) * 1024 + n]);
      *reinterpret_cast<u16x8*>(
          dst + ((size_t)base8 + (size_t)(nt * 8 + kc) * 64 + ln) * 8) = v;
    }
  }
}

// ---------------------------------------------------------------------------
__device__ __forceinline__ int swz(int row, int bytecol, int rowbytes) {
  return (row * rowbytes + bytecol) ^ ((row & 7) << 4);
}

// ---------------------------------------------------------------------------
// k_proj: P[1024 x 304] = text @ [ref_w|off_w|aw_w|0] + bias (r15-proven).
// ---------------------------------------------------------------------------
__global__ __launch_bounds__(1024) void k_proj(
    const float* __restrict__ text, const u16* __restrict__ pkp,
    const float* __restrict__ ref_b, const float* __restrict__ off_b,
    const float* __restrict__ aw_b, float* __restrict__ P) {
  __shared__ u16 aT[16 * 256];
  const int tid = threadIdx.x;
  const int lane = tid & 63, wv = tid >> 6;
  const int l15 = lane & 15, lg = lane >> 4;
  const size_t r0 = (size_t)blockIdx.x * 16;
  const f32x4 z4 = {0.f, 0.f, 0.f, 0.f};
  {
    int row = wv, c0 = lane * 4;
    const float* src = text + (r0 + row) * 256 + c0;
    u16x4 v;
#pragma unroll
    for (int j = 0; j < 4; ++j) v[j] = f2bf(src[j]);
    *reinterpret_cast<u16x4*>(reinterpret_cast<char*>(aT) + swz(row, c0 * 2, 512)) = v;
  }
  __syncthreads();
  const int nrep = (wv < 3) ? 2 : 1;
  for (int rep = 0; rep < nrep; ++rep) {
    int nt = wv + rep * 16;     // 0..18
    f32x4 acc = z4;
#pragma unroll
    for (int half = 0; half < 2; ++half) {
      bf16x8 b4[4];
#pragma unroll
      for (int i = 0; i < 4; ++i)
        b4[i] = *reinterpret_cast<const bf16x8*>(pkp + ((size_t)(nt * 8 + half * 4 + i) * 64 + lane) * 8);
#pragma unroll
      for (int i = 0; i < 4; ++i) {
        int kc = half * 4 + i;
        bf16x8 a = *reinterpret_cast<const bf16x8*>(
            reinterpret_cast<const char*>(aT) + swz(l15, kc * 64 + lg * 16, 512));
        acc = __builtin_amdgcn_mfma_f32_16x16x32_bf16(a, b4[i], acc, 0, 0, 0);
      }
    }
    int col = nt * 16 + l15;
    float bias = (col < 6) ? ref_b[col]
               : (col < 198) ? off_b[col - 6]
               : (col < 294) ? aw_b[col - 198] : 0.f;
#pragma unroll
    for (int r = 0; r < 4; ++r) {
      int m = lg * 4 + r;
      P[(r0 + m) * 304 + col] = acc[r] + bias;
    }
  }
}

// ---------------------------------------------------------------------------
// K2 v5: gather only; AGG partials written as bf16 (u16x8, 16B/thread).
// 2048 blocks, XCD-remapped. Gather math unchanged (r16/r17-proven).
// ---------------------------------------------------------------------------
__global__ __launch_bounds__(256) void k2_fused(
    const float* __restrict__ P, const float* __restrict__ vis,
    const unsigned char* __restrict__ mask,
    u16* __restrict__ AGG, float* __restrict__ CSUM) {
  __shared__ float p_s[304];
  __shared__ float ref_s[6];
  __shared__ float aw_s[96];
  const int tid = threadIdx.x;
  const int xcd = blockIdx.x & 7;
  const int idx = blockIdx.x >> 3;        // 0..255
  const int b = xcd * 2 + (idx >> 7);
  const int rem = idx & 127;
  const int bq = b * 64 + (rem >> 1);
  const int hf = rem & 1;
  p_s[tid] = P[(size_t)bq * 304 + tid];
  if (tid < 48) p_s[256 + tid] = P[(size_t)bq * 304 + 256 + tid];
  __syncthreads();
  if (tid < 6) ref_s[tid] = 1.f / (1.f + expf(-p_s[tid]));
  if (tid >= 8 && tid < 16) {
    int hh = tid - 8;
    float mx = -3.4e38f;
    for (int j = 0; j < 12; ++j) mx = fmaxf(mx, p_s[198 + hh * 12 + j]);
    float e[12]; float s = 0.f;
    for (int j = 0; j < 12; ++j) { e[j] = expf(p_s[198 + hh * 12 + j] - mx); s += e[j]; }
    float inv = 1.f / s;
    for (int j = 0; j < 12; ++j) aw_s[hh * 12 + j] = e[j] * inv;
  }
  __syncthreads();

  const int h = tid >> 5, d = tid & 31;
  float agg[8] = {0.f, 0.f, 0.f, 0.f, 0.f, 0.f, 0.f, 0.f};
  float csum = 0.f;
  const unsigned char* maskb = mask + (size_t)b * S_TOT;
  const float* visb = vis + (size_t)b * S_TOT * 256 + d * 8;

  auto do_point = [&](int l, int p, int Wl, int st) {
    const float Wf = (float)Wl;
    const int ip = (h * 3 + l) * 4 + p;
    const float rx = ref_s[l * 2 + 0], ry = ref_s[l * 2 + 1];
    const float ox = p_s[6 + ip * 2 + 0], oy = p_s[6 + ip * 2 + 1];
    const float aww = aw_s[ip];
    const float x = (rx + ox / Wf) * Wf - 0.5f;
    const float y = (ry + oy / Wf) * Wf - 0.5f;   // Hl == Wl (square levels)
    const float x0f = floorf(x), y0f = floorf(y);
    const float fx = x - x0f, fy = y - y0f;
    const int ix0 = (int)x0f, iy0 = (int)y0f;
    const bool xv0 = (unsigned)ix0 < (unsigned)Wl;
    const bool xv1 = (unsigned)(ix0 + 1) < (unsigned)Wl;
    const bool yv0 = (unsigned)iy0 < (unsigned)Wl;
    const bool yv1 = (unsigned)(iy0 + 1) < (unsigned)Wl;
    const int cx0 = min(max(ix0, 0), Wl - 1), cx1 = min(max(ix0 + 1, 0), Wl - 1);
    const int cy0 = min(max(iy0, 0), Wl - 1), cy1 = min(max(iy0 + 1, 0), Wl - 1);
    const int s00 = st + cy0 * Wl + cx0, s10 = st + cy0 * Wl + cx1;
    const int s01 = st + cy1 * Wl + cx0, s11 = st + cy1 * Wl + cx1;
    float w00 = (yv0 && xv0 && !maskb[s00]) ? aww * (1.f - fx) * (1.f - fy) : 0.f;
    float w10 = (yv0 && xv1 && !maskb[s10]) ? aww * fx * (1.f - fy) : 0.f;
    float w01 = (yv1 && xv0 && !maskb[s01]) ? aww * (1.f - fx) * fy : 0.f;
    float w11 = (yv1 && xv1 && !maskb[s11]) ? aww * fx * fy : 0.f;
    csum += w00 + w10 + w01 + w11;
    const float* p00 = visb + (size_t)s00 * 256;
    const float* p10 = visb + (size_t)s10 * 256;
    const float* p01 = visb + (size_t)s01 * 256;
    const float* p11 = visb + (size_t)s11 * 256;
    float4 a0 = *reinterpret_cast<const float4*>(p00);
    float4 a1 = *reinterpret_cast<const float4*>(p00 + 4);
    float4 b0 = *reinterpret_cast<const float4*>(p10);
    float4 b1 = *reinterpret_cast<const float4*>(p10 + 4);
    float4 c0 = *reinterpret_cast<const float4*>(p01);
    float4 c1 = *reinterpret_cast<const float4*>(p01 + 4);
    float4 e0 = *reinterpret_cast<const float4*>(p11);
    float4 e1 = *reinterpret_cast<const float4*>(p11 + 4);
    agg[0] += w00 * a0.x + w10 * b0.x + w01 * c0.x + w11 * e0.x;
    agg[1] += w00 * a0.y + w10 * b0.y + w01 * c0.y + w11 * e0.y;
    agg[2] += w00 * a0.z + w10 * b0.z + w01 * c0.z + w11 * e0.z;
    agg[3] += w00 * a0.w + w10 * b0.w + w01 * c0.w + w11 * e0.w;
    agg[4] += w00 * a1.x + w10 * b1.x + w01 * c1.x + w11 * e1.x;
    agg[5] += w00 * a1.y + w10 * b1.y + w01 * c1.y + w11 * e1.y;
    agg[6] += w00 * a1.z + w10 * b1.z + w01 * c1.z + w11 * e1.z;
    agg[7] += w00 * a1.w + w10 * b1.w + w01 * c1.w + w11 * e1.w;
  };

  if (hf == 0) {
    do_point(0, 0, 96, 0);
    do_point(0, 1, 96, 0);
    do_point(0, 2, 96, 0);
    do_point(0, 3, 96, 0);
    do_point(1, 0, 48, 9216);
    do_point(1, 1, 48, 9216);
  } else {
    do_point(1, 2, 48, 9216);
    do_point(1, 3, 48, 9216);
    do_point(2, 0, 24, 11520);
    do_point(2, 1, 24, 11520);
    do_point(2, 2, 24, 11520);
    do_point(2, 3, 24, 11520);
  }
  u16x8 v;
#pragma unroll
  for (int j = 0; j < 8; ++j) v[j] = f2bf(agg[j]);
  *reinterpret_cast<u16x8*>(AGG + (((size_t)hf * 1024 + bq) * 8 + h) * 256 + d * 8) = v;
  if (d == 0) CSUM[((size_t)hf * 1024 + bq) * 8 + h] = csum;
}

// ---------------------------------------------------------------------------
// K3 v5: k_ctx merged as phase 0. 64 blocks x 16 waves.
// Phase0: aG[16][2048] = bf16(AGG0+AGG1) -> MFMA vs packed val_w -> aA (ctx).
// Then proj -> out(+text) -> LN1 -> f1 -> f2 -> LN2 (r12-proven phases).
// aG (64KB) aliases the later aA/aY/aH/fb block (lifetimes disjoint).
// ---------------------------------------------------------------------------
__global__ __launch_bounds__(1024) void k3_mfma(
    const u16* __restrict__ AGG, const float* __restrict__ CSUM,
    const float* __restrict__ text, const u16* __restrict__ pk,
    const float* __restrict__ val_b,
    const float* __restrict__ proj_b, const float* __restrict__ out_b,
    const float* __restrict__ n1_g, const float* __restrict__ n1_b,
    const float* __restrict__ f1_b, const float* __restrict__ f2_b,
    const float* __restrict__ n2_g, const float* __restrict__ n2_b,
    float* __restrict__ outp) {
  __shared__ char lds[65536];               // 64 KB, phase-dependent layout
  u16* aG = (u16*)lds;                      // phase0: [16][2048] bf16 swz4096
  u16* aA = (u16*)lds;                      // [16][256] bf16 swz512
  u16* aY = (u16*)(lds + 8192);             // [16][256]
  u16* aH = (u16*)(lds + 16384);            // [16][1024] swz2048
  float* fb = (float*)(lds + 49152);        // [16][256] fp32
  __shared__ float cs_s[16][8];

  const int tid = threadIdx.x;
  const int lane = tid & 63, wv = tid >> 6;
  const int l15 = lane & 15, lg = lane >> 4;
  const size_t r0 = (size_t)blockIdx.x * 16;
  const f32x4 z4 = {0.f, 0.f, 0.f, 0.f};

  // ---- phase 0: ctx = (AGG0+AGG1) @ val_w + csum*val_b -> registers ----
  {
    int row = tid >> 6, c0 = (tid & 63) * 32;
    const u16* s0 = AGG + ((size_t)(r0 + row)) * 2048 + c0;
    const u16* s1 = s0 + (size_t)1024 * 2048;
#pragma unroll
    for (int j = 0; j < 4; ++j) {
      u16x8 x = *reinterpret_cast<const u16x8*>(s0 + j * 8);
      u16x8 y = *reinterpret_cast<const u16x8*>(s1 + j * 8);
      u16x8 v;
#pragma unroll
      for (int e = 0; e < 8; ++e) v[e] = f2bf(bf2f(x[e]) + bf2f(y[e]));
      *reinterpret_cast<u16x8*>(reinterpret_cast<char*>(aG) +
                                swz(row, (c0 + j * 8) * 2, 4096)) = v;
    }
    if (tid < 128) {
      int rr = tid >> 3, hh = tid & 7;
      cs_s[rr][hh] = CSUM[(r0 + rr) * 8 + hh] + CSUM[(1024 + r0 + rr) * 8 + hh];
    }
  }
  __syncthreads();
  f32x4 ctxacc;
  {
    const u16* pkv = pk + (size_t)91648 * 8;
    const int h = wv >> 1;
    bf16x8 b8[8];
#pragma unroll
    for (int kc = 0; kc < 8; ++kc)
      b8[kc] = *reinterpret_cast<const bf16x8*>(pkv + ((size_t)(wv * 8 + kc) * 64 + lane) * 8);
    f32x4 acc = z4;
#pragma unroll
    for (int kc = 0; kc < 8; ++kc) {
      bf16x8 a = *reinterpret_cast<const bf16x8*>(
          reinterpret_cast<const char*>(aG) + swz(l15, h * 512 + kc * 64 + lg * 16, 4096));
      acc = __builtin_amdgcn_mfma_f32_16x16x32_bf16(a, b8[kc], acc, 0, 0, 0);
    }
    int col = wv * 16 + l15;
    float vb = val_b[col];
#pragma unroll
    for (int r = 0; r < 4; ++r) ctxacc[r] = acc[r] + cs_s[lg * 4 + r][h] * vb;
  }
  __syncthreads();   // all aG reads done before aA overwrite
  {  // write ctx (bf16) into aA via C/D layout
    int col = wv * 16 + l15;
#pragma unroll
    for (int r = 0; r < 4; ++r) {
      int m = lg * 4 + r;
      *reinterpret_cast<u16*>(reinterpret_cast<char*>(aA) + swz(m, col * 2, 512)) =
          f2bf(ctxacc[r]);
    }
  }
  __syncthreads();

  // ---- proj: y = ctx @ proj_w + proj_b -> aY ----
  {
    f32x4 acc = z4;
#pragma unroll
    for (int half = 0; half < 2; ++half) {
      bf16x8 b4[4];
#pragma unroll
      for (int i = 0; i < 4; ++i)
        b4[i] = *reinterpret_cast<const bf16x8*>(pk + ((wv * 8 + half * 4 + i) * 64 + lane) * 8);
#pragma unroll
      for (int i = 0; i < 4; ++i) {
        int kc = half * 4 + i;
        bf16x8 a = *reinterpret_cast<const bf16x8*>(
            reinterpret_cast<const char*>(aA) + swz(l15, kc * 64 + lg * 16, 512));
        acc = __builtin_amdgcn_mfma_f32_16x16x32_bf16(a, b4[i], acc, 0, 0, 0);
      }
    }
    int col = wv * 16 + l15;
    float bias = proj_b[col];
#pragma unroll
    for (int r = 0; r < 4; ++r) {
      int m = lg * 4 + r;
      *reinterpret_cast<u16*>(reinterpret_cast<char*>(aY) + swz(m, col * 2, 512)) =
          f2bf(acc[r] + bias);
    }
  }
  __syncthreads();

  // ---- out: y2 = y @ out_w + out_b + text -> fb ----
  {
    const u16* pko = pk + 65536;
    f32x4 acc = z4;
#pragma unroll
    for (int half = 0; half < 2; ++half) {
      bf16x8 b4[4];
#pragma unroll
      for (int i = 0; i < 4; ++i)
        b4[i] = *reinterpret_cast<const bf16x8*>(pko + ((wv * 8 + half * 4 + i) * 64 + lane) * 8);
#pragma unroll
      for (int i = 0; i < 4; ++i) {
        int kc = half * 4 + i;
        bf16x8 a = *reinterpret_cast<const bf16x8*>(
            reinterpret_cast<const char*>(aY) + swz(l15, kc * 64 + lg * 16, 512));
        acc = __builtin_amdgcn_mfma_f32_16x16x32_bf16(a, b4[i], acc, 0, 0, 0);
      }
    }
    int col = wv * 16 + l15;
    float bias = out_b[col];
#pragma unroll
    for (int r = 0; r < 4; ++r) {
      int m = lg * 4 + r;
      fb[m * 256 + col] = acc[r] + bias + text[(r0 + m) * 256 + col];
    }
  }
  __syncthreads();

  // ---- LN1 -> fb + aA ----
  {
    int row = wv;
    float s = 0.f;
#pragma unroll
    for (int j = 0; j < 4; ++j) s += fb[row * 256 + lane + j * 64];
#pragma unroll
    for (int o = 1; o < 64; o <<= 1) s += __shfl_xor(s, o, 64);
    float mu = s * 0.00390625f;
    float vs = 0.f;
#pragma unroll
    for (int j = 0; j < 4; ++j) {
      float dd = fb[row * 256 + lane + j * 64] - mu; vs += dd * dd;
    }
#pragma unroll
    for (int o = 1; o < 64; o <<= 1) vs += __shfl_xor(vs, o, 64);
    float rs = rsqrtf(vs * 0.00390625f + 1e-5f);
#pragma unroll
    for (int j = 0; j < 4; ++j) {
      int col = lane + j * 64;
      float v = (fb[row * 256 + col] - mu) * rs * n1_g[col] + n1_b[col];
      fb[row * 256 + col] = v;
      *reinterpret_cast<u16*>(reinterpret_cast<char*>(aA) + swz(row, col * 2, 512)) = f2bf(v);
    }
  }
  __syncthreads();

  // ---- f1 -> aH ----
  {
    const u16* pkf1 = pk + 131072;
#pragma unroll
    for (int nt = 0; nt < 4; ++nt) {
      int ntg = wv * 4 + nt;
      f32x4 acc = z4;
#pragma unroll
      for (int half = 0; half < 2; ++half) {
        bf16x8 b4[4];
#pragma unroll
        for (int i = 0; i < 4; ++i)
          b4[i] = *reinterpret_cast<const bf16x8*>(pkf1 + ((ntg * 8 + half * 4 + i) * 64 + lane) * 8);
#pragma unroll
        for (int i = 0; i < 4; ++i) {
          int kc = half * 4 + i;
          bf16x8 a = *reinterpret_cast<const bf16x8*>(
              reinterpret_cast<const char*>(aA) + swz(l15, kc * 64 + lg * 16, 512));
          acc = __builtin_amdgcn_mfma_f32_16x16x32_bf16(a, b4[i], acc, 0, 0, 0);
        }
      }
      int col = ntg * 16 + l15;
      float bias = f1_b[col];
#pragma unroll
      for (int r = 0; r < 4; ++r) {
        int m = lg * 4 + r;
        *reinterpret_cast<u16*>(reinterpret_cast<char*>(aH) + swz(m, col * 2, 2048)) =
            f2bf(fmaxf(acc[r] + bias, 0.f));
      }
    }
  }
  __syncthreads();

  // ---- f2 -> fb ----
  {
    const u16* pkf2 = pk + 393216;
    f32x4 acc = z4;
#pragma unroll
    for (int c = 0; c < 8; ++c) {
      bf16x8 b4[4];
#pragma unroll
      for (int i = 0; i < 4; ++i)
        b4[i] = *reinterpret_cast<const bf16x8*>(pkf2 + ((wv * 32 + c * 4 + i) * 64 + lane) * 8);
#pragma unroll
      for (int i = 0; i < 4; ++i) {
        int kc = c * 4 + i;
        bf16x8 a = *reinterpret_cast<const bf16x8*>(
            reinterpret_cast<const char*>(aH) + swz(l15, kc * 64 + lg * 16, 2048));
        acc = __builtin_amdgcn_mfma_f32_16x16x32_bf16(a, b4[i], acc, 0, 0, 0);
      }
    }
    int col = wv * 16 + l15;
    float bias = f2_b[col];
#pragma unroll
    for (int r = 0; r < 4; ++r) {
      int m = lg * 4 + r;
      fb[m * 256 + col] = acc[r] + bias + fb[m * 256 + col];
    }
  }
  __syncthreads();

  // ---- LN2 -> out ----
  {
    int row = wv;
    float s = 0.f;
#pragma unroll
    for (int j = 0; j < 4; ++j) s += fb[row * 256 + lane + j * 64];
#pragma unroll
    for (int o = 1; o < 64; o <<= 1) s += __shfl_xor(s, o, 64);
    float mu = s * 0.00390625f;
    float vs = 0.f;
#pragma unroll
    for (int j = 0; j < 4; ++j) {
      float dd = fb[row * 256 + lane + j * 64] - mu; vs += dd * dd;
    }
#pragma unroll
    for (int o = 1; o < 64; o <<= 1) vs += __shfl_xor(vs, o, 64);
    float rs = rsqrtf(vs * 0.00390625f + 1e-5f);
#pragma unroll
    for (int j = 0; j < 4; ++j) {
      int col = lane + j * 64;
      outp[(r0 + row) * 256 + col] = (fb[row * 256 + col] - mu) * rs * n2_g[col] + n2_b[col];
    }
  }
}

// ---------------------------------------------------------------------------
extern "C" void kernel_launch(void* const* d_in, const int* in_sizes, int n_in,
                              void* d_out, int out_size, void* d_ws, size_t ws_size,
                              hipStream_t stream) {
  const float* text  = (const float*)d_in[0];
  const float* vis   = (const float*)d_in[1];
  const unsigned char* mask = (const unsigned char*)d_in[4];
  const float* ref_w = (const float*)d_in[5];
  const float* ref_b = (const float*)d_in[6];
  const float* off_w = (const float*)d_in[7];
  const float* off_b = (const float*)d_in[8];
  const float* aw_w  = (const float*)d_in[9];
  const float* aw_b  = (const float*)d_in[10];
  const float* val_w = (const float*)d_in[11];
  const float* val_b = (const float*)d_in[12];
  const float* proj_w = (const float*)d_in[13];
  const float* proj_b = (const float*)d_in[14];
  const float* out_w = (const float*)d_in[15];
  const float* out_b = (const float*)d_in[16];
  const float* n1_g  = (const float*)d_in[17];
  const float* n1_b  = (const float*)d_in[18];
  const float* f1_w  = (const float*)d_in[19];
  const float* f1_b  = (const float*)d_in[20];
  const float* f2_w  = (const float*)d_in[21];
  const float* f2_b  = (const float*)d_in[22];
  const float* n2_g  = (const float*)d_in[23];
  const float* n2_b  = (const float*)d_in[24];
  float* outp = (float*)d_out;

  char* ws = (char*)d_ws;
  u16* pk    = (u16*)ws;                                // [0, ~1.6 MB)
  u16* pkp   = pk + (size_t)81920 * 8;                  // proj fragments
  float* P   = (float*)(ws + (size_t)2 * 1024 * 1024);  // [2, 3.25 MB)
  u16* AGG   = (u16*)(ws + (size_t)4 * 1024 * 1024);    // [4, 12 MB) bf16
  float* CSUM = (float*)(ws + (size_t)13 * 1024 * 1024);// 64 KB

  k_pack<<<82, 256, 0, stream>>>(proj_w, out_w, f1_w, f2_w, val_w,
                                 ref_w, off_w, aw_w, pk);
  k_proj<<<64, 1024, 0, stream>>>(text, pkp, ref_b, off_b, aw_b, P);
  k2_fused<<<2048, 256, 0, stream>>>(P, vis, mask, AGG, CSUM);
  k3_mfma<<<64, 1024, 0, stream>>>(AGG, CSUM, text, pk, val_b, proj_b, out_b,
                                   n1_g, n1_b, f1_b, f2_b, n2_g, n2_b, outp);
}